// Round 11
// baseline (472.529 us; speedup 1.0000x reference)
//
#include <hip/hip_runtime.h>

// SimpleConcatAttention on MI355X — round 11: pipelined conv_key + fused mask.
// Round-10 post-mortem: swizzle killed the conflicts (7.6e6->2.6e5) but
// conv_key stayed 79 µs @ 2.5 TB/s -> it was LATENCY-bound (8192 tiny blocks,
// serial load->LDS->barrier->store chain, ~5 blocks/CU TLP), not conflict-bound.
// Round 11: (a) conv_key processes 4 n-tiles per block, issuing tile t+1's
// loads BEFORE tile t's barrier — HBM latency hides under the transpose phase;
// (b) masking moves into phase-2's epilogue (mask read amortized under the
// compute-bound GEMM; S written pre-masked with -inf), so softmax drops its
// 67 MB mask read. Everything else identical to round 10.

typedef float f32x4 __attribute__((ext_vector_type(4)));
typedef short s16x8 __attribute__((ext_vector_type(8)));
typedef short s16x4 __attribute__((ext_vector_type(4)));
typedef _Float16 f16x8 __attribute__((ext_vector_type(8)));
typedef unsigned short u16;
typedef unsigned short u16x8 __attribute__((ext_vector_type(8)));

// ---- conversions (compiler-visible; no inline asm per m240 lesson) ----
__device__ __forceinline__ u16 f2h(float f) {           // f32 -> fp16 RNE
    _Float16 h = (_Float16)f;
    return __builtin_bit_cast(u16, h);
}
__device__ __forceinline__ float h2f(u16 v) {           // exact expand
    return (float)__builtin_bit_cast(_Float16, v);
}
__device__ __forceinline__ u16 f2bf(float f) {          // bf16 RNE (fallback path)
    unsigned int u = __float_as_uint(f);
    return (u16)((u + 0x7fffu + ((u >> 16) & 1u)) >> 16);
}
__device__ __forceinline__ float bf2f(u16 h) {
    return __uint_as_float(((unsigned int)h) << 16);
}

// Load 8 u16 (two 8B halves) from LDS at two precomputed u16 offsets.
__device__ __forceinline__ s16x8 ld2(const u16* p, int off1, int off2) {
    s16x4 a = *(const s16x4*)(p + off1);
    s16x4 b = *(const s16x4*)(p + off2);
    s16x8 r = {a[0], a[1], a[2], a[3], b[0], b[1], b[2], b[3]};
    return r;
}
__device__ __forceinline__ f16x8 ld2h(const u16* p, int off1, int off2) {
    return __builtin_bit_cast(f16x8, ld2(p, off1, off2));
}

// Transpose-tile address (64x64 u16, col-major, stride 72): element (r, c)
// lives at col c, physical row-block (r>>3)^sigma(c), low bits r&7.
// sigma(c) = (c ^ (c>>3)) & 7 spreads scatter WRITES over all 32 banks;
// reads of 8 consecutive rows stay one aligned u16x8 (proven round 10:
// conflicts 7.6e6 -> 2.6e5).
__device__ __forceinline__ int tpos(int c, int rblk, int rlow) {
    const int s = (c ^ (c >> 3)) & 7;
    return c * 72 + 8 * ((rblk ^ s) & 7) + rlow;
}

// ===========================================================================
// Round-1 fused-conversion bf16 GEMM — fallback path only (ws too small).
// ===========================================================================
#define CSTR 36
typedef short bf16x8 __attribute__((ext_vector_type(8)));
__device__ __forceinline__ int swzc(int row, int k) {
    return row * CSTR + (k ^ (((row >> 2) & 7) << 2));
}
__device__ __forceinline__ bf16x8 ld_fragc(const u16* plane, int row, int kg) {
    s16x8 v = ld2(plane, swzc(row, kg), swzc(row, kg + 16));
    return __builtin_bit_cast(bf16x8, v);
}

template<bool BT, bool SPLIT>
__global__ __launch_bounds__(256, 2) void gemm_f32conv(
    const float* __restrict__ A, const float* __restrict__ B,
    float* __restrict__ C,
    int Kd, int lda, int ldb, int ldc,
    long sA, long sB, long sC, float scale)
{
    constexpr int PLANES = SPLIT ? 2 : 1;
    __shared__ u16 As[PLANES][128 * CSTR];
    __shared__ u16 Bs[PLANES][128 * CSTR];

    const int tid  = threadIdx.x;
    const int lane = tid & 63;
    const int wave = tid >> 6;
    const int wm = (wave >> 1) * 64, wn = (wave & 1) * 64;
    const int lr = lane & 15, kg = (lane >> 4) * 4;

    const int m0 = blockIdx.y * 128, n0 = blockIdx.x * 128;
    const float* Ag = A + (long)blockIdx.z * sA + (long)m0 * lda;
    const float* Bg = B + (long)blockIdx.z * sB + (BT ? (long)n0 * ldb : (long)n0);

    f32x4 acc[4][4] = {};

    for (int k0 = 0; k0 < Kd; k0 += 32) {
        __syncthreads();
#pragma unroll
        for (int it = 0; it < 4; it++) {
            const int idx = tid + it * 256;
            const int row = idx >> 3, kc = (idx & 7) * 4;
            f32x4 v = *(const f32x4*)(Ag + (long)row * lda + k0 + kc);
            ushort4 h;
            h.x = f2bf(v[0]); h.y = f2bf(v[1]); h.z = f2bf(v[2]); h.w = f2bf(v[3]);
            *(ushort4*)&As[0][swzc(row, kc)] = h;
            if constexpr (SPLIT) {
                ushort4 l;
                l.x = f2bf(v[0] - bf2f(h.x)); l.y = f2bf(v[1] - bf2f(h.y));
                l.z = f2bf(v[2] - bf2f(h.z)); l.w = f2bf(v[3] - bf2f(h.w));
                *(ushort4*)&As[1][swzc(row, kc)] = l;
            }
        }
        if constexpr (BT) {
#pragma unroll
            for (int it = 0; it < 4; it++) {
                const int idx = tid + it * 256;
                const int row = idx >> 3, kc = (idx & 7) * 4;
                f32x4 v = *(const f32x4*)(Bg + (long)row * ldb + k0 + kc);
                ushort4 h;
                h.x = f2bf(v[0]); h.y = f2bf(v[1]); h.z = f2bf(v[2]); h.w = f2bf(v[3]);
                *(ushort4*)&Bs[0][swzc(row, kc)] = h;
                if constexpr (SPLIT) {
                    ushort4 l;
                    l.x = f2bf(v[0] - bf2f(h.x)); l.y = f2bf(v[1] - bf2f(h.y));
                    l.z = f2bf(v[2] - bf2f(h.z)); l.w = f2bf(v[3] - bf2f(h.w));
                    *(ushort4*)&Bs[1][swzc(row, kc)] = l;
                }
            }
        } else {
#pragma unroll
            for (int it = 0; it < 2; it++) {
                const int idx = tid + it * 256;
                const int kk = (idx >> 5) * 2;
                const int nc = (idx & 31) * 4;
                f32x4 v0 = *(const f32x4*)(Bg + (long)(k0 + kk) * ldb + nc);
                f32x4 v1 = *(const f32x4*)(Bg + (long)(k0 + kk + 1) * ldb + nc);
#pragma unroll
                for (int e = 0; e < 4; e++) {
                    const u16 h0 = f2bf(v0[e]), h1 = f2bf(v1[e]);
                    *(unsigned*)&Bs[0][swzc(nc + e, kk)] =
                        (unsigned)h0 | ((unsigned)h1 << 16);
                    if constexpr (SPLIT) {
                        const u16 l0 = f2bf(v0[e] - bf2f(h0));
                        const u16 l1 = f2bf(v1[e] - bf2f(h1));
                        *(unsigned*)&Bs[1][swzc(nc + e, kk)] =
                            (unsigned)l0 | ((unsigned)l1 << 16);
                    }
                }
            }
        }
        __syncthreads();

        bf16x8 ah[4], bh[4], al[4], bl[4];
#pragma unroll
        for (int i = 0; i < 4; i++) {
            ah[i] = ld_fragc(&As[0][0], wm + i * 16 + lr, kg);
            if constexpr (SPLIT) al[i] = ld_fragc(&As[1][0], wm + i * 16 + lr, kg);
        }
#pragma unroll
        for (int j = 0; j < 4; j++) {
            bh[j] = ld_fragc(&Bs[0][0], wn + j * 16 + lr, kg);
            if constexpr (SPLIT) bl[j] = ld_fragc(&Bs[1][0], wn + j * 16 + lr, kg);
        }
#pragma unroll
        for (int i = 0; i < 4; i++)
#pragma unroll
            for (int j = 0; j < 4; j++) {
                acc[i][j] = __builtin_amdgcn_mfma_f32_16x16x32_bf16(
                    ah[i], bh[j], acc[i][j], 0, 0, 0);
                if constexpr (SPLIT) {
                    acc[i][j] = __builtin_amdgcn_mfma_f32_16x16x32_bf16(
                        ah[i], bl[j], acc[i][j], 0, 0, 0);
                    acc[i][j] = __builtin_amdgcn_mfma_f32_16x16x32_bf16(
                        al[i], bh[j], acc[i][j], 0, 0, 0);
                }
            }
    }

    float* Cg = C + (long)blockIdx.z * sC + (long)(m0 + wm) * ldc + n0 + wn;
    const int rbase = (lane >> 4) * 4;
#pragma unroll
    for (int i = 0; i < 4; i++)
#pragma unroll
        for (int r = 0; r < 4; r++) {
            float* cp = Cg + (long)(i * 16 + rbase + r) * ldc + lr;
#pragma unroll
            for (int j = 0; j < 4; j++)
                cp[j * 16] = acc[i][j][r] * scale;
        }
}

// ===========================================================================
// split: src f32 -> fp16 hi/lo planes (query). n4 = elems/4.
// ===========================================================================
__global__ __launch_bounds__(256) void split_f16(
    const float* __restrict__ src, u16* __restrict__ hi, u16* __restrict__ lo,
    long n4)
{
    const long stride = (long)gridDim.x * 256;
    for (long i = (long)blockIdx.x * 256 + threadIdx.x; i < n4; i += stride) {
        f32x4 v = *(const f32x4*)(src + i * 4);
        ushort4 h, l;
        h.x = f2h(v[0]); h.y = f2h(v[1]); h.z = f2h(v[2]); h.w = f2h(v[3]);
        l.x = f2h(v[0] - h2f(h.x)); l.y = f2h(v[1] - h2f(h.y));
        l.z = f2h(v[2] - h2f(h.z)); l.w = f2h(v[3] - h2f(h.w));
        *(ushort4*)(hi + i * 4) = h;
        *(ushort4*)(lo + i * 4) = l;
    }
}

// ===========================================================================
// Fused key converter, PIPELINED: f32 key [Z][2048 n][1024 d] -> fp16 key_h
// (same layout) AND fp16 key_hT [Z][1024 d][2048 n].
// Each block: 64-d slab x 4 consecutive 64-n tiles (loop). Tile t+1's global
// loads issue BEFORE tile t's barrier, hiding HBM latency under the
// transpose-read/store phase. Swizzled tile (tpos) keeps scatters conflict-free.
// Grid: (16, 8, 16) = 2048 blocks.
// ===========================================================================
__global__ __launch_bounds__(256) void conv_key(
    const float* __restrict__ key, u16* __restrict__ kh, u16* __restrict__ khT)
{
    __shared__ u16 T[64 * 72];
    const int tid = threadIdx.x;
    const int d0 = blockIdx.x * 64;             // 16 slabs over d=1024
    const int nb = blockIdx.y * 256;            // 8 groups of 4x64 n
    const long zo = (long)blockIdx.z * 2048 * 1024;

    const int r  = tid >> 3;                    // 0..31 (upper half handled as r+32)
    const int c  = (tid & 7) * 8;               // d-col within tile
    const int rb = r >> 3, rl = r & 7;

    const float* sbase = key + zo + (long)nb * 1024 + d0;

    // preload tile 0 (static regs — rule #20)
    f32x4 p0a = *(const f32x4*)(sbase + (long)r * 1024 + c);
    f32x4 p0b = *(const f32x4*)(sbase + (long)r * 1024 + c + 4);
    f32x4 p1a = *(const f32x4*)(sbase + (long)(r + 32) * 1024 + c);
    f32x4 p1b = *(const f32x4*)(sbase + (long)(r + 32) * 1024 + c + 4);

#pragma unroll
    for (int t = 0; t < 4; t++) {
        const int n0 = nb + t * 64;
        // ---- convert tile t, write kh, scatter into swizzled T ----
        u16 h0[8], h1[8];
#pragma unroll
        for (int j = 0; j < 4; j++) {
            h0[j] = f2h(p0a[j]); h0[4 + j] = f2h(p0b[j]);
            h1[j] = f2h(p1a[j]); h1[4 + j] = f2h(p1b[j]);
        }
        u16x8 hv0 = {h0[0], h0[1], h0[2], h0[3], h0[4], h0[5], h0[6], h0[7]};
        u16x8 hv1 = {h1[0], h1[1], h1[2], h1[3], h1[4], h1[5], h1[6], h1[7]};
        *(u16x8*)(kh + zo + (long)(n0 + r) * 1024 + d0 + c) = hv0;
        *(u16x8*)(kh + zo + (long)(n0 + r + 32) * 1024 + d0 + c) = hv1;
#pragma unroll
        for (int j = 0; j < 8; j++) {
            T[tpos(c + j, rb, rl)]     = h0[j];
            T[tpos(c + j, rb + 4, rl)] = h1[j];
        }
        // ---- prefetch tile t+1 BEFORE the barrier (latency overlaps phase B) ----
        if (t < 3) {
            const float* s2 = sbase + (long)(t + 1) * 64 * 1024;
            p0a = *(const f32x4*)(s2 + (long)r * 1024 + c);
            p0b = *(const f32x4*)(s2 + (long)r * 1024 + c + 4);
            p1a = *(const f32x4*)(s2 + (long)(r + 32) * 1024 + c);
            p1b = *(const f32x4*)(s2 + (long)(r + 32) * 1024 + c + 4);
        }
        __syncthreads();
        // ---- phase B: contiguous u16x8 reads, coalesced khT stores ----
        u16* dt = khT + zo + (long)d0 * 2048 + n0;
#pragma unroll
        for (int it = 0; it < 2; it++) {
            const int cq = it * 32 + (tid >> 3);    // d-col within tile
            const int m  = tid & 7;                 // n row-block
            *(u16x8*)(dt + (long)cq * 2048 + m * 8) =
                *(const u16x8*)&T[tpos(cq, m, 0)];
        }
        __syncthreads();
    }
}

// ===========================================================================
// Fused W split+transpose: f32 W [1024 k][1024 n] -> fp16 hiT/loT [n][k].
// ===========================================================================
__global__ __launch_bounds__(256) void splitT_f16(
    const float* __restrict__ src, u16* __restrict__ hiT, u16* __restrict__ loT)
{
    __shared__ u16 Th[64 * 72];
    __shared__ u16 Tl[64 * 72];
    const int tid = threadIdx.x;
    const int c0 = blockIdx.x * 64;             // n-cols
    const int r0 = blockIdx.y * 64;             // k-rows
    const float* s = src + (long)r0 * 1024 + c0;
#pragma unroll
    for (int it = 0; it < 2; it++) {
        const int r = it * 32 + (tid >> 3);     // k-row within tile
        const int c = (tid & 7) * 8;            // n-col within tile
        f32x4 v0 = *(const f32x4*)(s + (long)r * 1024 + c);
        f32x4 v1 = *(const f32x4*)(s + (long)r * 1024 + c + 4);
        const int rb = r >> 3, rl = r & 7;
#pragma unroll
        for (int j = 0; j < 8; j++) {
            const float f = (j < 4) ? v0[j] : v1[j - 4];
            const u16 h = f2h(f);
            Th[tpos(c + j, rb, rl)] = h;
            Tl[tpos(c + j, rb, rl)] = f2h(f - h2f(h));
        }
    }
    __syncthreads();
    u16* dh = hiT + (long)c0 * 1024 + r0;
    u16* dl = loT + (long)c0 * 1024 + r0;
#pragma unroll
    for (int it = 0; it < 2; it++) {
        const int c = it * 32 + (tid >> 3);     // n-col within tile
        const int m = tid & 7;                  // k row-block
        *(u16x8*)(dh + (long)c * 1024 + m * 8) = *(const u16x8*)&Th[tpos(c, m, 0)];
        *(u16x8*)(dl + (long)c * 1024 + m * 8) = *(const u16x8*)&Tl[tpos(c, m, 0)];
    }
}

// ===========================================================================
// fp16 MFMA GEMM, BK=64: both operands k-contiguous, reg-staged (pad-72) with
// T14 prefetch. 32 MFMA per staging round. Tile 128x128, 4 waves (64x64 each).
// Optional fused mask (phase 2): C written pre-masked with -inf where mask==0
// (mask layout == C layout); reads amortize under the compute-bound loop.
// ===========================================================================
#define ASTR2 72
__global__ __launch_bounds__(256, 3) void gemm_f16(
    const u16* __restrict__ A, const u16* __restrict__ B,
    float* __restrict__ C, const int* __restrict__ mask,
    int Kd, int lda, int ldb, int ldc,
    long sA, long sB, long sC, float scale)
{
    __shared__ u16 As[128 * ASTR2];
    __shared__ u16 Bs[128 * ASTR2];

    const int tid  = threadIdx.x;
    const int lane = tid & 63;
    const int wave = tid >> 6;
    const int wm = (wave >> 1) * 64, wn = (wave & 1) * 64;
    const int lr = lane & 15, kg = (lane >> 4) * 4;

    const int m0 = blockIdx.y * 128, n0 = blockIdx.x * 128;
    const u16* Ag = A + (long)blockIdx.z * sA + (long)m0 * lda;
    const u16* Bg = B + (long)blockIdx.z * sB + (long)n0 * ldb;

    // Per-thread staging coords: row srow (2 threads/row), 32 cols at scol.
    const int srow = tid >> 1, scol = (tid & 1) * 32;

    // Prefetch registers (static indices only — rule #20): 4 x 16B per operand.
    u16x8 ra[4], rb[4];
#pragma unroll
    for (int it = 0; it < 4; it++) {
        ra[it] = *(const u16x8*)(Ag + (long)srow * lda + scol + it * 8);
        rb[it] = *(const u16x8*)(Bg + (long)srow * ldb + scol + it * 8);
    }

    f32x4 acc[4][4] = {};

    for (int k0 = 0; k0 < Kd; k0 += 64) {
        __syncthreads();
        // ---- STAGE_WRITE: regs (k-cols k0..k0+63) -> LDS ----
#pragma unroll
        for (int it = 0; it < 4; it++) {
            *(u16x8*)&As[srow * ASTR2 + scol + it * 8] = ra[it];
            *(u16x8*)&Bs[srow * ASTR2 + scol + it * 8] = rb[it];
        }
        __syncthreads();

        // ---- STAGE_LOAD (T14): issue next 64-k tile before the MFMA phase ----
        if (k0 + 64 < Kd) {
            const int kn = k0 + 64;
#pragma unroll
            for (int it = 0; it < 4; it++) {
                ra[it] = *(const u16x8*)(Ag + (long)srow * lda + kn + scol + it * 8);
                rb[it] = *(const u16x8*)(Bg + (long)srow * ldb + kn + scol + it * 8);
            }
        }

        // ---- two k=32 sub-phases: {8 frag loads + 16 MFMA} each ----
#pragma unroll
        for (int s = 0; s < 2; s++) {
            const int kb = s * 32 + kg;
            f16x8 af[4], bfr[4];
#pragma unroll
            for (int i = 0; i < 4; i++) {
                const int r = wm + i * 16 + lr;
                af[i] = ld2h(As, r * ASTR2 + kb, r * ASTR2 + kb + 16);
            }
#pragma unroll
            for (int j = 0; j < 4; j++) {
                const int r = wn + j * 16 + lr;
                bfr[j] = ld2h(Bs, r * ASTR2 + kb, r * ASTR2 + kb + 16);
            }
#pragma unroll
            for (int i = 0; i < 4; i++)
#pragma unroll
                for (int j = 0; j < 4; j++)
                    acc[i][j] = __builtin_amdgcn_mfma_f32_16x16x32_f16(
                        af[i], bfr[j], acc[i][j], 0, 0, 0);
        }
    }

    // ---- epilogue: C/D layout col=lane&15, row=(lane>>4)*4+reg ----
    float* Cg = C + (long)blockIdx.z * sC + (long)(m0 + wm) * ldc + n0 + wn;
    const int* Mg = mask ? mask + (long)blockIdx.z * sC
                                + (long)(m0 + wm) * ldc + n0 + wn : nullptr;
    const int rbase = (lane >> 4) * 4;
#pragma unroll
    for (int i = 0; i < 4; i++)
#pragma unroll
        for (int r = 0; r < 4; r++) {
            const long ro = (long)(i * 16 + rbase + r) * ldc + lr;
            float* cp = Cg + ro;
            if (Mg) {
                const int* mp = Mg + ro;
#pragma unroll
                for (int j = 0; j < 4; j++)
                    cp[j * 16] = mp[j * 16] ? acc[i][j][r] * scale : -INFINITY;
            } else {
#pragma unroll
                for (int j = 0; j < 4; j++)
                    cp[j * 16] = acc[i][j][r] * scale;
            }
        }
}

// ===========================================================================
// Phase-1 kernel: qW = (query @ W)/32, 3-term fp16-split in, fp16 OUT.
// M=512, N=1024, K=1024, B = W^T planes [n][k]. Tile 64x64, 4 waves (32x32),
// 128 blocks; copy staging (pad-40), both operands k-contiguous.
// ===========================================================================
#define ASTR 40
__global__ __launch_bounds__(256, 2) void gemm_qw(
    const u16* __restrict__ qh, const u16* __restrict__ ql,
    const u16* __restrict__ WhT, const u16* __restrict__ WlT,
    u16* __restrict__ qWh)
{
    __shared__ u16 As[2][64 * ASTR];
    __shared__ u16 Bs[2][64 * ASTR];

    const int tid  = threadIdx.x;
    const int lane = tid & 63;
    const int wave = tid >> 6;
    const int wm = (wave >> 1) * 32, wn = (wave & 1) * 32;
    const int lr = lane & 15, kg = (lane >> 4) * 4;
    const int m0 = blockIdx.y * 64, n0 = blockIdx.x * 64;

    const u16* Ag[2] = { qh + (long)m0 * 1024, ql + (long)m0 * 1024 };
    const u16* Bg[2] = { WhT + (long)n0 * 1024, WlT + (long)n0 * 1024 };

    f32x4 acc[2][2] = {};

    for (int k0 = 0; k0 < 1024; k0 += 32) {
        __syncthreads();
        const int row = tid >> 2, kc = (tid & 3) * 8;   // 64 rows x 32 k per plane
#pragma unroll
        for (int p = 0; p < 2; p++) {
            *(u16x8*)&As[p][row * ASTR + kc] =
                *(const u16x8*)(Ag[p] + (long)row * 1024 + k0 + kc);
            *(u16x8*)&Bs[p][row * ASTR + kc] =
                *(const u16x8*)(Bg[p] + (long)row * 1024 + k0 + kc);
        }
        __syncthreads();

        f16x8 af[2][2], bfr[2][2];
#pragma unroll
        for (int i = 0; i < 2; i++) {
            const int r = wm + i * 16 + lr;
#pragma unroll
            for (int p = 0; p < 2; p++)
                af[p][i] = ld2h(&As[p][0], r * ASTR + kg, r * ASTR + kg + 16);
        }
#pragma unroll
        for (int j = 0; j < 2; j++) {
            const int r = wn + j * 16 + lr;
#pragma unroll
            for (int p = 0; p < 2; p++)
                bfr[p][j] = ld2h(&Bs[p][0], r * ASTR + kg, r * ASTR + kg + 16);
        }
#pragma unroll
        for (int i = 0; i < 2; i++)
#pragma unroll
            for (int j = 0; j < 2; j++) {
                acc[i][j] = __builtin_amdgcn_mfma_f32_16x16x32_f16(
                    af[0][i], bfr[0][j], acc[i][j], 0, 0, 0);
                acc[i][j] = __builtin_amdgcn_mfma_f32_16x16x32_f16(
                    af[0][i], bfr[1][j], acc[i][j], 0, 0, 0);
                acc[i][j] = __builtin_amdgcn_mfma_f32_16x16x32_f16(
                    af[1][i], bfr[0][j], acc[i][j], 0, 0, 0);
            }
    }

    // Epilogue: scale by 1/32, write fp16 qW.
    const int rbase = (lane >> 4) * 4;
#pragma unroll
    for (int i = 0; i < 2; i++)
#pragma unroll
        for (int r = 0; r < 4; r++) {
            const long ro = (long)(m0 + wm + i * 16 + rbase + r) * 1024 + n0 + wn + lr;
#pragma unroll
            for (int j = 0; j < 2; j++)
                qWh[ro + j * 16] = f2h(acc[i][j][r] * (1.f / 32.f));
        }
}

// ===========================================================================
// Masked softmax over rows of 2048, in place on f32 scores; optionally also
// writes an fp16 copy (phase-4 A operand). One block per row.
// mask may be nullptr: scores already pre-masked with -inf (ws path).
// ===========================================================================
__global__ __launch_bounds__(256) void softmax_rows(
    float* __restrict__ att, const int* __restrict__ mask, u16* __restrict__ ahf)
{
    const int  row  = blockIdx.x;                    // b*512 + k
    const int  tid  = threadIdx.x;
    const long base = (long)row * 2048 + tid * 8;

    f32x4 s0 = *(const f32x4*)(att + base);
    f32x4 s1 = *(const f32x4*)(att + base + 4);
    float x[8] = {s0[0], s0[1], s0[2], s0[3], s1[0], s1[1], s1[2], s1[3]};

    if (mask) {
        int4 mv0 = *(const int4*)(mask + base);
        int4 mv1 = *(const int4*)(mask + base + 4);
        const int mk[8] = {mv0.x, mv0.y, mv0.z, mv0.w, mv1.x, mv1.y, mv1.z, mv1.w};
#pragma unroll
        for (int j = 0; j < 8; j++) x[j] = mk[j] ? x[j] : -INFINITY;
    }

    float mx = x[0];
#pragma unroll
    for (int j = 1; j < 8; j++) mx = fmaxf(mx, x[j]);
#pragma unroll
    for (int off = 32; off > 0; off >>= 1) mx = fmaxf(mx, __shfl_down(mx, off));

    __shared__ float red[8];
    const int wave = tid >> 6, lane = tid & 63;
    if (lane == 0) red[wave] = mx;
    __syncthreads();
    mx = fmaxf(fmaxf(red[0], red[1]), fmaxf(red[2], red[3]));

    if (mx == -INFINITY) {                           // all-masked row: zeros, not NaN
        f32x4 z = {0.f, 0.f, 0.f, 0.f};
        *(f32x4*)(att + base) = z;
        *(f32x4*)(att + base + 4) = z;
        if (ahf) {
            u16x8 zh = {0, 0, 0, 0, 0, 0, 0, 0};
            *(u16x8*)(ahf + base) = zh;
        }
        return;
    }

    float e[8], s = 0.f;
#pragma unroll
    for (int j = 0; j < 8; j++) { e[j] = __expf(x[j] - mx); s += e[j]; }
#pragma unroll
    for (int off = 32; off > 0; off >>= 1) s += __shfl_down(s, off);
    if (lane == 0) red[4 + wave] = s;
    __syncthreads();
    s = red[4] + red[5] + red[6] + red[7];

    const float inv = 1.f / s;
    float o[8];
#pragma unroll
    for (int j = 0; j < 8; j++) o[j] = e[j] * inv;
    f32x4 o0 = {o[0], o[1], o[2], o[3]}, o1 = {o[4], o[5], o[6], o[7]};
    *(f32x4*)(att + base) = o0;
    *(f32x4*)(att + base + 4) = o1;
    if (ahf) {
        u16x8 ph;
#pragma unroll
        for (int j = 0; j < 8; j++) ph[j] = f2h(o[j]);
        *(u16x8*)(ahf + base) = ph;
    }
}

// ===========================================================================
extern "C" void kernel_launch(void* const* d_in, const int* in_sizes, int n_in,
                              void* d_out, int out_size, void* d_ws, size_t ws_size,
                              hipStream_t stream)
{
    const float* query = nullptr;   // 512*1024      = 524288
    const float* key   = nullptr;   // 16*2048*1024  = 33554432
    const float* W     = nullptr;   // 1024*1024     = 1048576
    const int*   mask  = nullptr;   // 16*512*2048   = 16777216
    for (int i = 0; i < n_in; i++) {
        switch (in_sizes[i]) {
            case 524288:   query = (const float*)d_in[i]; break;
            case 33554432: key   = (const float*)d_in[i]; break;
            case 1048576:  W     = (const float*)d_in[i]; break;
            case 16777216: mask  = (const int*)d_in[i];   break;
        }
    }

    float* out = (float*)d_out;                     // [16,512,1024] f32
    float* att = out + (long)16 * 512 * 1024;       // [16,512,2048] f32

    const long KEY_E = 16L * 2048 * 1024;           // 33,554,432
    const long ATT_E = 16L * 512 * 2048;            // 16,777,216
    const long QW_E  = 512L * 1024;                 //    524,288
    const long W_E   = 1024L * 1024;                //  1,048,576
    // ws layout (same footprint/guard as rounds 4-10):
    //   key_h | key_hT | att_h | qW_h
    // Phase-1 scratch (q hi/lo, W^T hi/lo = 3.1M u16) aliases into the att_h
    // region (16.8M u16, dead until softmax).
    const size_t WS_NEED = (size_t)(2 * KEY_E + ATT_E + 2 * QW_E) * 2;

    if (ws_size >= WS_NEED && d_ws != nullptr) {
        u16* key_h  = (u16*)d_ws;
        u16* key_hT = key_h + KEY_E;
        u16* att_h  = key_hT + KEY_E;
        u16* qW_h   = att_h + ATT_E;
        // phase-1 scratch aliased into att_h (all dead by softmax time):
        u16* q_hi   = att_h;
        u16* q_lo   = q_hi + QW_E;
        u16* W_hiT  = q_lo + QW_E;
        u16* W_loT  = W_hiT + W_E;

        // 0) key f32 -> key_h AND key_hT, pipelined 4-tile blocks
        conv_key<<<dim3(16, 8, 16), 256, 0, stream>>>(key, key_h, key_hT);
        // 0b) q -> fp16 hi+lo; W -> transposed fp16 hi+lo in ONE pass
        split_f16<<<dim3(512), 256, 0, stream>>>(query, q_hi, q_lo, QW_E / 4);
        splitT_f16<<<dim3(16, 16, 1), 256, 0, stream>>>(W, W_hiT, W_loT);

        // 1) qW = (query @ W) / 32  [512 x 1024], 3-term fp16 split, fp16 out
        gemm_qw<<<dim3(16, 8, 1), 256, 0, stream>>>(
            q_hi, q_lo, W_hiT, W_loT, qW_h);

        // 2) S[b] = qW @ key[b]^T, pre-masked with -inf (fused mask epilogue)
        gemm_f16<<<dim3(16, 4, 16), 256, 0, stream>>>(
            qW_h, key_h, att, mask,
            1024, 1024, 1024, 2048,
            0L, (long)2048 * 1024, (long)512 * 2048, 1.f);

        // 3) softmax (no mask read — S pre-masked), dual-write f32 + fp16
        softmax_rows<<<dim3(16 * 512), 256, 0, stream>>>(att, nullptr, att_h);

        // 4) out[b] = att[b] @ key[b]  [512 x 1024], K=2048, 1-term fp16, BK=64
        gemm_f16<<<dim3(8, 4, 16), 256, 0, stream>>>(
            att_h, key_hT, out, nullptr,
            2048, 2048, 2048, 1024,
            (long)512 * 2048, (long)1024 * 2048, (long)512 * 1024, 1.f);
    } else {
        // -------- fallback: round-1 bf16 path, no workspace --------
        float* qW = out;    // f32 scratch in out region (dead before phase 4)
        gemm_f32conv<false, true><<<dim3(8, 4, 1), 256, 0, stream>>>(
            query, W, qW, 1024, 1024, 1024, 1024, 0L, 0L, 0L, 1.f / 32.f);
        gemm_f32conv<true, true><<<dim3(16, 4, 16), 256, 0, stream>>>(
            qW, key, att, 1024, 1024, 1024, 2048,
            0L, (long)2048 * 1024, (long)512 * 2048, 1.f);
        softmax_rows<<<dim3(16 * 512), 256, 0, stream>>>(att, mask, nullptr);
        gemm_f32conv<false, false><<<dim3(8, 4, 16), 256, 0, stream>>>(
            att, key, out, 2048, 2048, 1024, 1024,
            (long)512 * 2048, (long)2048 * 1024, (long)512 * 1024, 1.f);
    }
}

// Round 12
// 458.158 us; speedup vs baseline: 1.0314x; 1.0314x over previous
//
#include <hip/hip_runtime.h>

// SimpleConcatAttention on MI355X — round 12: consolidation to best-measured parts.
// Round-11 post-mortem: mask fusion regressed BOTH gemm_f16 instantiations
// (epilogue scatter loads + shared-binary codegen, rule 19) -> reverted.
// Accounting also shows round-9's conv_key fusion was itself a ~25 µs LOSS
// (separate conv ~35 + transpose ~22 never hit top-5 in round 8; fused = 79-82):
// the fused kernel serializes load->convert->scatter->barrier->store in one
// small-LDS chain, while split passes are pure 5-6 TB/s streams.
// Round 12 = round-10 base with conv_key UN-fused:
//   0a) conv_f16: key f32 -> key_h fp16 (grid-stride stream)
//   0b) transpose_u16: key_h -> key_hT (tpos-swizzled tile, proven conflict-free)
//   0c) split_f16 (query), splitT_f16 (W -> W^T hi/lo, one pass)
//   1) qW 3-term fp16-split GEMM   2) S 1-term fp16 BK=64 GEMM
//   3) masked softmax (dual-write f32 + fp16)   4) out 1-term fp16 BK=64 GEMM
// Fallback (ws too small): round-1 bf16 fused-conversion path.

typedef float f32x4 __attribute__((ext_vector_type(4)));
typedef short s16x8 __attribute__((ext_vector_type(8)));
typedef short s16x4 __attribute__((ext_vector_type(4)));
typedef _Float16 f16x8 __attribute__((ext_vector_type(8)));
typedef unsigned short u16;
typedef unsigned short u16x8 __attribute__((ext_vector_type(8)));

// ---- conversions (compiler-visible; no inline asm per m240 lesson) ----
__device__ __forceinline__ u16 f2h(float f) {           // f32 -> fp16 RNE
    _Float16 h = (_Float16)f;
    return __builtin_bit_cast(u16, h);
}
__device__ __forceinline__ float h2f(u16 v) {           // exact expand
    return (float)__builtin_bit_cast(_Float16, v);
}
__device__ __forceinline__ u16 f2bf(float f) {          // bf16 RNE (fallback path)
    unsigned int u = __float_as_uint(f);
    return (u16)((u + 0x7fffu + ((u >> 16) & 1u)) >> 16);
}
__device__ __forceinline__ float bf2f(u16 h) {
    return __uint_as_float(((unsigned int)h) << 16);
}

// Load 8 u16 (two 8B halves) from LDS at two precomputed u16 offsets.
__device__ __forceinline__ s16x8 ld2(const u16* p, int off1, int off2) {
    s16x4 a = *(const s16x4*)(p + off1);
    s16x4 b = *(const s16x4*)(p + off2);
    s16x8 r = {a[0], a[1], a[2], a[3], b[0], b[1], b[2], b[3]};
    return r;
}
__device__ __forceinline__ f16x8 ld2h(const u16* p, int off1, int off2) {
    return __builtin_bit_cast(f16x8, ld2(p, off1, off2));
}

// Transpose-tile address (64x64 u16, col-major, stride 72): element (r, c)
// lives at col c, physical row-block (r>>3)^sigma(c), low bits r&7.
// sigma(c) = (c ^ (c>>3)) & 7 spreads scatter WRITES over all 32 banks;
// reads of 8 consecutive rows stay one aligned u16x8 (proven round 10:
// conflicts 7.6e6 -> 2.6e5).
__device__ __forceinline__ int tpos(int c, int rblk, int rlow) {
    const int s = (c ^ (c >> 3)) & 7;
    return c * 72 + 8 * ((rblk ^ s) & 7) + rlow;
}

// ===========================================================================
// Round-1 fused-conversion bf16 GEMM — fallback path only (ws too small).
// ===========================================================================
#define CSTR 36
typedef short bf16x8 __attribute__((ext_vector_type(8)));
__device__ __forceinline__ int swzc(int row, int k) {
    return row * CSTR + (k ^ (((row >> 2) & 7) << 2));
}
__device__ __forceinline__ bf16x8 ld_fragc(const u16* plane, int row, int kg) {
    s16x8 v = ld2(plane, swzc(row, kg), swzc(row, kg + 16));
    return __builtin_bit_cast(bf16x8, v);
}

template<bool BT, bool SPLIT>
__global__ __launch_bounds__(256, 2) void gemm_f32conv(
    const float* __restrict__ A, const float* __restrict__ B,
    float* __restrict__ C,
    int Kd, int lda, int ldb, int ldc,
    long sA, long sB, long sC, float scale)
{
    constexpr int PLANES = SPLIT ? 2 : 1;
    __shared__ u16 As[PLANES][128 * CSTR];
    __shared__ u16 Bs[PLANES][128 * CSTR];

    const int tid  = threadIdx.x;
    const int lane = tid & 63;
    const int wave = tid >> 6;
    const int wm = (wave >> 1) * 64, wn = (wave & 1) * 64;
    const int lr = lane & 15, kg = (lane >> 4) * 4;

    const int m0 = blockIdx.y * 128, n0 = blockIdx.x * 128;
    const float* Ag = A + (long)blockIdx.z * sA + (long)m0 * lda;
    const float* Bg = B + (long)blockIdx.z * sB + (BT ? (long)n0 * ldb : (long)n0);

    f32x4 acc[4][4] = {};

    for (int k0 = 0; k0 < Kd; k0 += 32) {
        __syncthreads();
#pragma unroll
        for (int it = 0; it < 4; it++) {
            const int idx = tid + it * 256;
            const int row = idx >> 3, kc = (idx & 7) * 4;
            f32x4 v = *(const f32x4*)(Ag + (long)row * lda + k0 + kc);
            ushort4 h;
            h.x = f2bf(v[0]); h.y = f2bf(v[1]); h.z = f2bf(v[2]); h.w = f2bf(v[3]);
            *(ushort4*)&As[0][swzc(row, kc)] = h;
            if constexpr (SPLIT) {
                ushort4 l;
                l.x = f2bf(v[0] - bf2f(h.x)); l.y = f2bf(v[1] - bf2f(h.y));
                l.z = f2bf(v[2] - bf2f(h.z)); l.w = f2bf(v[3] - bf2f(h.w));
                *(ushort4*)&As[1][swzc(row, kc)] = l;
            }
        }
        if constexpr (BT) {
#pragma unroll
            for (int it = 0; it < 4; it++) {
                const int idx = tid + it * 256;
                const int row = idx >> 3, kc = (idx & 7) * 4;
                f32x4 v = *(const f32x4*)(Bg + (long)row * ldb + k0 + kc);
                ushort4 h;
                h.x = f2bf(v[0]); h.y = f2bf(v[1]); h.z = f2bf(v[2]); h.w = f2bf(v[3]);
                *(ushort4*)&Bs[0][swzc(row, kc)] = h;
                if constexpr (SPLIT) {
                    ushort4 l;
                    l.x = f2bf(v[0] - bf2f(h.x)); l.y = f2bf(v[1] - bf2f(h.y));
                    l.z = f2bf(v[2] - bf2f(h.z)); l.w = f2bf(v[3] - bf2f(h.w));
                    *(ushort4*)&Bs[1][swzc(row, kc)] = l;
                }
            }
        } else {
#pragma unroll
            for (int it = 0; it < 2; it++) {
                const int idx = tid + it * 256;
                const int kk = (idx >> 5) * 2;
                const int nc = (idx & 31) * 4;
                f32x4 v0 = *(const f32x4*)(Bg + (long)(k0 + kk) * ldb + nc);
                f32x4 v1 = *(const f32x4*)(Bg + (long)(k0 + kk + 1) * ldb + nc);
#pragma unroll
                for (int e = 0; e < 4; e++) {
                    const u16 h0 = f2bf(v0[e]), h1 = f2bf(v1[e]);
                    *(unsigned*)&Bs[0][swzc(nc + e, kk)] =
                        (unsigned)h0 | ((unsigned)h1 << 16);
                    if constexpr (SPLIT) {
                        const u16 l0 = f2bf(v0[e] - bf2f(h0));
                        const u16 l1 = f2bf(v1[e] - bf2f(h1));
                        *(unsigned*)&Bs[1][swzc(nc + e, kk)] =
                            (unsigned)l0 | ((unsigned)l1 << 16);
                    }
                }
            }
        }
        __syncthreads();

        bf16x8 ah[4], bh[4], al[4], bl[4];
#pragma unroll
        for (int i = 0; i < 4; i++) {
            ah[i] = ld_fragc(&As[0][0], wm + i * 16 + lr, kg);
            if constexpr (SPLIT) al[i] = ld_fragc(&As[1][0], wm + i * 16 + lr, kg);
        }
#pragma unroll
        for (int j = 0; j < 4; j++) {
            bh[j] = ld_fragc(&Bs[0][0], wn + j * 16 + lr, kg);
            if constexpr (SPLIT) bl[j] = ld_fragc(&Bs[1][0], wn + j * 16 + lr, kg);
        }
#pragma unroll
        for (int i = 0; i < 4; i++)
#pragma unroll
            for (int j = 0; j < 4; j++) {
                acc[i][j] = __builtin_amdgcn_mfma_f32_16x16x32_bf16(
                    ah[i], bh[j], acc[i][j], 0, 0, 0);
                if constexpr (SPLIT) {
                    acc[i][j] = __builtin_amdgcn_mfma_f32_16x16x32_bf16(
                        ah[i], bl[j], acc[i][j], 0, 0, 0);
                    acc[i][j] = __builtin_amdgcn_mfma_f32_16x16x32_bf16(
                        al[i], bh[j], acc[i][j], 0, 0, 0);
                }
            }
    }

    float* Cg = C + (long)blockIdx.z * sC + (long)(m0 + wm) * ldc + n0 + wn;
    const int rbase = (lane >> 4) * 4;
#pragma unroll
    for (int i = 0; i < 4; i++)
#pragma unroll
        for (int r = 0; r < 4; r++) {
            float* cp = Cg + (long)(i * 16 + rbase + r) * ldc + lr;
#pragma unroll
            for (int j = 0; j < 4; j++)
                cp[j * 16] = acc[i][j][r] * scale;
        }
}

// ===========================================================================
// Streaming converters.
// ===========================================================================
__global__ __launch_bounds__(256) void conv_f16(
    const float* __restrict__ src, u16* __restrict__ dst, long n4)
{
    const long stride = (long)gridDim.x * 256;
    for (long i = (long)blockIdx.x * 256 + threadIdx.x; i < n4; i += stride) {
        f32x4 v = *(const f32x4*)(src + i * 4);
        ushort4 h;
        h.x = f2h(v[0]); h.y = f2h(v[1]); h.z = f2h(v[2]); h.w = f2h(v[3]);
        *(ushort4*)(dst + i * 4) = h;
    }
}

__global__ __launch_bounds__(256) void split_f16(
    const float* __restrict__ src, u16* __restrict__ hi, u16* __restrict__ lo,
    long n4)
{
    const long stride = (long)gridDim.x * 256;
    for (long i = (long)blockIdx.x * 256 + threadIdx.x; i < n4; i += stride) {
        f32x4 v = *(const f32x4*)(src + i * 4);
        ushort4 h, l;
        h.x = f2h(v[0]); h.y = f2h(v[1]); h.z = f2h(v[2]); h.w = f2h(v[3]);
        l.x = f2h(v[0] - h2f(h.x)); l.y = f2h(v[1] - h2f(h.y));
        l.z = f2h(v[2] - h2f(h.z)); l.w = f2h(v[3] - h2f(h.w));
        *(ushort4*)(hi + i * 4) = h;
        *(ushort4*)(lo + i * 4) = l;
    }
}

// ===========================================================================
// Batched u16 transpose: in [Z][R][C] -> out [Z][C][R]. R,C multiples of 64.
// tpos-swizzled 64x64 tile: conflict-free scatter writes, contiguous reads.
// ===========================================================================
__global__ __launch_bounds__(256) void transpose_u16(
    const u16* __restrict__ in, u16* __restrict__ out, int R, int C)
{
    __shared__ u16 T[64 * 72];
    const int tid = threadIdx.x;
    const int c0 = blockIdx.x * 64, r0 = blockIdx.y * 64;
    const long zo = (long)blockIdx.z * R * C;
    const u16* src = in + zo + (long)r0 * C + c0;
#pragma unroll
    for (int it = 0; it < 2; it++) {
        const int r = it * 32 + (tid >> 3), c = (tid & 7) * 8;
        u16x8 v = *(const u16x8*)(src + (long)r * C + c);
        const int rb = r >> 3, rl = r & 7;
#pragma unroll
        for (int j = 0; j < 8; j++) T[tpos(c + j, rb, rl)] = v[j];
    }
    __syncthreads();
    u16* dst = out + zo + (long)c0 * R + r0;
#pragma unroll
    for (int it = 0; it < 2; it++) {
        const int c = it * 32 + (tid >> 3);
        const int m = tid & 7;
        *(u16x8*)(dst + (long)c * R + m * 8) = *(const u16x8*)&T[tpos(c, m, 0)];
    }
}

// ===========================================================================
// Fused W split+transpose: f32 W [1024 k][1024 n] -> fp16 hiT/loT [n][k].
// (Small enough that fusion wins here: one read of W, both planes written.)
// ===========================================================================
__global__ __launch_bounds__(256) void splitT_f16(
    const float* __restrict__ src, u16* __restrict__ hiT, u16* __restrict__ loT)
{
    __shared__ u16 Th[64 * 72];
    __shared__ u16 Tl[64 * 72];
    const int tid = threadIdx.x;
    const int c0 = blockIdx.x * 64;             // n-cols
    const int r0 = blockIdx.y * 64;             // k-rows
    const float* s = src + (long)r0 * 1024 + c0;
#pragma unroll
    for (int it = 0; it < 2; it++) {
        const int r = it * 32 + (tid >> 3);     // k-row within tile
        const int c = (tid & 7) * 8;            // n-col within tile
        f32x4 v0 = *(const f32x4*)(s + (long)r * 1024 + c);
        f32x4 v1 = *(const f32x4*)(s + (long)r * 1024 + c + 4);
        const int rb = r >> 3, rl = r & 7;
#pragma unroll
        for (int j = 0; j < 8; j++) {
            const float f = (j < 4) ? v0[j] : v1[j - 4];
            const u16 h = f2h(f);
            Th[tpos(c + j, rb, rl)] = h;
            Tl[tpos(c + j, rb, rl)] = f2h(f - h2f(h));
        }
    }
    __syncthreads();
    u16* dh = hiT + (long)c0 * 1024 + r0;
    u16* dl = loT + (long)c0 * 1024 + r0;
#pragma unroll
    for (int it = 0; it < 2; it++) {
        const int c = it * 32 + (tid >> 3);     // n-col within tile
        const int m = tid & 7;                  // k row-block
        *(u16x8*)(dh + (long)c * 1024 + m * 8) = *(const u16x8*)&Th[tpos(c, m, 0)];
        *(u16x8*)(dl + (long)c * 1024 + m * 8) = *(const u16x8*)&Tl[tpos(c, m, 0)];
    }
}

// ===========================================================================
// fp16 MFMA GEMM, BK=64: both operands k-contiguous, reg-staged (pad-72) with
// T14 prefetch. 32 MFMA per staging round. Tile 128x128, 4 waves (64x64 each).
// (Round-10 form — no mask parameter; codegen restored.)
// ===========================================================================
#define ASTR2 72
__global__ __launch_bounds__(256, 3) void gemm_f16(
    const u16* __restrict__ A, const u16* __restrict__ B,
    float* __restrict__ C,
    int Kd, int lda, int ldb, int ldc,
    long sA, long sB, long sC, float scale)
{
    __shared__ u16 As[128 * ASTR2];
    __shared__ u16 Bs[128 * ASTR2];

    const int tid  = threadIdx.x;
    const int lane = tid & 63;
    const int wave = tid >> 6;
    const int wm = (wave >> 1) * 64, wn = (wave & 1) * 64;
    const int lr = lane & 15, kg = (lane >> 4) * 4;

    const int m0 = blockIdx.y * 128, n0 = blockIdx.x * 128;
    const u16* Ag = A + (long)blockIdx.z * sA + (long)m0 * lda;
    const u16* Bg = B + (long)blockIdx.z * sB + (long)n0 * ldb;

    // Per-thread staging coords: row srow (2 threads/row), 32 cols at scol.
    const int srow = tid >> 1, scol = (tid & 1) * 32;

    // Prefetch registers (static indices only — rule #20): 4 x 16B per operand.
    u16x8 ra[4], rb[4];
#pragma unroll
    for (int it = 0; it < 4; it++) {
        ra[it] = *(const u16x8*)(Ag + (long)srow * lda + scol + it * 8);
        rb[it] = *(const u16x8*)(Bg + (long)srow * ldb + scol + it * 8);
    }

    f32x4 acc[4][4] = {};

    for (int k0 = 0; k0 < Kd; k0 += 64) {
        __syncthreads();
        // ---- STAGE_WRITE: regs (k-cols k0..k0+63) -> LDS ----
#pragma unroll
        for (int it = 0; it < 4; it++) {
            *(u16x8*)&As[srow * ASTR2 + scol + it * 8] = ra[it];
            *(u16x8*)&Bs[srow * ASTR2 + scol + it * 8] = rb[it];
        }
        __syncthreads();

        // ---- STAGE_LOAD (T14): issue next 64-k tile before the MFMA phase ----
        if (k0 + 64 < Kd) {
            const int kn = k0 + 64;
#pragma unroll
            for (int it = 0; it < 4; it++) {
                ra[it] = *(const u16x8*)(Ag + (long)srow * lda + kn + scol + it * 8);
                rb[it] = *(const u16x8*)(Bg + (long)srow * ldb + kn + scol + it * 8);
            }
        }

        // ---- two k=32 sub-phases: {8 frag loads + 16 MFMA} each ----
#pragma unroll
        for (int s = 0; s < 2; s++) {
            const int kb = s * 32 + kg;
            f16x8 af[4], bfr[4];
#pragma unroll
            for (int i = 0; i < 4; i++) {
                const int r = wm + i * 16 + lr;
                af[i] = ld2h(As, r * ASTR2 + kb, r * ASTR2 + kb + 16);
            }
#pragma unroll
            for (int j = 0; j < 4; j++) {
                const int r = wn + j * 16 + lr;
                bfr[j] = ld2h(Bs, r * ASTR2 + kb, r * ASTR2 + kb + 16);
            }
#pragma unroll
            for (int i = 0; i < 4; i++)
#pragma unroll
                for (int j = 0; j < 4; j++)
                    acc[i][j] = __builtin_amdgcn_mfma_f32_16x16x32_f16(
                        af[i], bfr[j], acc[i][j], 0, 0, 0);
        }
    }

    // ---- epilogue: C/D layout col=lane&15, row=(lane>>4)*4+reg ----
    float* Cg = C + (long)blockIdx.z * sC + (long)(m0 + wm) * ldc + n0 + wn;
    const int rbase = (lane >> 4) * 4;
#pragma unroll
    for (int i = 0; i < 4; i++)
#pragma unroll
        for (int r = 0; r < 4; r++) {
            float* cp = Cg + (long)(i * 16 + rbase + r) * ldc + lr;
#pragma unroll
            for (int j = 0; j < 4; j++)
                cp[j * 16] = acc[i][j][r] * scale;
        }
}

// ===========================================================================
// Phase-1 kernel: qW = (query @ W)/32, 3-term fp16-split in, fp16 OUT.
// M=512, N=1024, K=1024, B = W^T planes [n][k]. Tile 64x64, 4 waves (32x32),
// 128 blocks; copy staging (pad-40), both operands k-contiguous.
// ===========================================================================
#define ASTR 40
__global__ __launch_bounds__(256, 2) void gemm_qw(
    const u16* __restrict__ qh, const u16* __restrict__ ql,
    const u16* __restrict__ WhT, const u16* __restrict__ WlT,
    u16* __restrict__ qWh)
{
    __shared__ u16 As[2][64 * ASTR];
    __shared__ u16 Bs[2][64 * ASTR];

    const int tid  = threadIdx.x;
    const int lane = tid & 63;
    const int wave = tid >> 6;
    const int wm = (wave >> 1) * 32, wn = (wave & 1) * 32;
    const int lr = lane & 15, kg = (lane >> 4) * 4;
    const int m0 = blockIdx.y * 64, n0 = blockIdx.x * 64;

    const u16* Ag[2] = { qh + (long)m0 * 1024, ql + (long)m0 * 1024 };
    const u16* Bg[2] = { WhT + (long)n0 * 1024, WlT + (long)n0 * 1024 };

    f32x4 acc[2][2] = {};

    for (int k0 = 0; k0 < 1024; k0 += 32) {
        __syncthreads();
        const int row = tid >> 2, kc = (tid & 3) * 8;   // 64 rows x 32 k per plane
#pragma unroll
        for (int p = 0; p < 2; p++) {
            *(u16x8*)&As[p][row * ASTR + kc] =
                *(const u16x8*)(Ag[p] + (long)row * 1024 + k0 + kc);
            *(u16x8*)&Bs[p][row * ASTR + kc] =
                *(const u16x8*)(Bg[p] + (long)row * 1024 + k0 + kc);
        }
        __syncthreads();

        f16x8 af[2][2], bfr[2][2];
#pragma unroll
        for (int i = 0; i < 2; i++) {
            const int r = wm + i * 16 + lr;
#pragma unroll
            for (int p = 0; p < 2; p++)
                af[p][i] = ld2h(&As[p][0], r * ASTR + kg, r * ASTR + kg + 16);
        }
#pragma unroll
        for (int j = 0; j < 2; j++) {
            const int r = wn + j * 16 + lr;
#pragma unroll
            for (int p = 0; p < 2; p++)
                bfr[p][j] = ld2h(&Bs[p][0], r * ASTR + kg, r * ASTR + kg + 16);
        }
#pragma unroll
        for (int i = 0; i < 2; i++)
#pragma unroll
            for (int j = 0; j < 2; j++) {
                acc[i][j] = __builtin_amdgcn_mfma_f32_16x16x32_f16(
                    af[0][i], bfr[0][j], acc[i][j], 0, 0, 0);
                acc[i][j] = __builtin_amdgcn_mfma_f32_16x16x32_f16(
                    af[0][i], bfr[1][j], acc[i][j], 0, 0, 0);
                acc[i][j] = __builtin_amdgcn_mfma_f32_16x16x32_f16(
                    af[1][i], bfr[0][j], acc[i][j], 0, 0, 0);
            }
    }

    // Epilogue: scale by 1/32, write fp16 qW.
    const int rbase = (lane >> 4) * 4;
#pragma unroll
    for (int i = 0; i < 2; i++)
#pragma unroll
        for (int r = 0; r < 4; r++) {
            const long ro = (long)(m0 + wm + i * 16 + rbase + r) * 1024 + n0 + wn + lr;
#pragma unroll
            for (int j = 0; j < 2; j++)
                qWh[ro + j * 16] = f2h(acc[i][j][r] * (1.f / 32.f));
        }
}

// ===========================================================================
// Masked softmax over rows of 2048, in place on f32 scores; optionally also
// writes an fp16 copy (phase-4 A operand). One block per row.
// ===========================================================================
__global__ __launch_bounds__(256) void softmax_rows(
    float* __restrict__ att, const int* __restrict__ mask, u16* __restrict__ ahf)
{
    const int  row  = blockIdx.x;                    // b*512 + k
    const int  tid  = threadIdx.x;
    const long base = (long)row * 2048 + tid * 8;

    f32x4 s0 = *(const f32x4*)(att + base);
    f32x4 s1 = *(const f32x4*)(att + base + 4);
    int4  mv0 = *(const int4*)(mask + base);
    int4  mv1 = *(const int4*)(mask + base + 4);
    const int mk[8] = {mv0.x, mv0.y, mv0.z, mv0.w, mv1.x, mv1.y, mv1.z, mv1.w};

    float x[8] = {s0[0], s0[1], s0[2], s0[3], s1[0], s1[1], s1[2], s1[3]};
#pragma unroll
    for (int j = 0; j < 8; j++) x[j] = mk[j] ? x[j] : -INFINITY;

    float mx = x[0];
#pragma unroll
    for (int j = 1; j < 8; j++) mx = fmaxf(mx, x[j]);
#pragma unroll
    for (int off = 32; off > 0; off >>= 1) mx = fmaxf(mx, __shfl_down(mx, off));

    __shared__ float red[8];
    const int wave = tid >> 6, lane = tid & 63;
    if (lane == 0) red[wave] = mx;
    __syncthreads();
    mx = fmaxf(fmaxf(red[0], red[1]), fmaxf(red[2], red[3]));

    if (mx == -INFINITY) {                           // all-masked row: zeros, not NaN
        f32x4 z = {0.f, 0.f, 0.f, 0.f};
        *(f32x4*)(att + base) = z;
        *(f32x4*)(att + base + 4) = z;
        if (ahf) {
            u16x8 zh = {0, 0, 0, 0, 0, 0, 0, 0};
            *(u16x8*)(ahf + base) = zh;
        }
        return;
    }

    float e[8], s = 0.f;
#pragma unroll
    for (int j = 0; j < 8; j++) { e[j] = __expf(x[j] - mx); s += e[j]; }
#pragma unroll
    for (int off = 32; off > 0; off >>= 1) s += __shfl_down(s, off);
    if (lane == 0) red[4 + wave] = s;
    __syncthreads();
    s = red[4] + red[5] + red[6] + red[7];

    const float inv = 1.f / s;
    float o[8];
#pragma unroll
    for (int j = 0; j < 8; j++) o[j] = e[j] * inv;
    f32x4 o0 = {o[0], o[1], o[2], o[3]}, o1 = {o[4], o[5], o[6], o[7]};
    *(f32x4*)(att + base) = o0;
    *(f32x4*)(att + base + 4) = o1;
    if (ahf) {
        u16x8 ph;
#pragma unroll
        for (int j = 0; j < 8; j++) ph[j] = f2h(o[j]);
        *(u16x8*)(ahf + base) = ph;
    }
}

// ===========================================================================
extern "C" void kernel_launch(void* const* d_in, const int* in_sizes, int n_in,
                              void* d_out, int out_size, void* d_ws, size_t ws_size,
                              hipStream_t stream)
{
    const float* query = nullptr;   // 512*1024      = 524288
    const float* key   = nullptr;   // 16*2048*1024  = 33554432
    const float* W     = nullptr;   // 1024*1024     = 1048576
    const int*   mask  = nullptr;   // 16*512*2048   = 16777216
    for (int i = 0; i < n_in; i++) {
        switch (in_sizes[i]) {
            case 524288:   query = (const float*)d_in[i]; break;
            case 33554432: key   = (const float*)d_in[i]; break;
            case 1048576:  W     = (const float*)d_in[i]; break;
            case 16777216: mask  = (const int*)d_in[i];   break;
        }
    }

    float* out = (float*)d_out;                     // [16,512,1024] f32
    float* att = out + (long)16 * 512 * 1024;       // [16,512,2048] f32

    const long KEY_E = 16L * 2048 * 1024;           // 33,554,432
    const long ATT_E = 16L * 512 * 2048;            // 16,777,216
    const long QW_E  = 512L * 1024;                 //    524,288
    const long W_E   = 1024L * 1024;                //  1,048,576
    // ws layout (same footprint/guard as rounds 4-11):
    //   key_h | key_hT | att_h | qW_h
    // Phase-1 scratch (q hi/lo, W^T hi/lo = 3.1M u16) aliases into the att_h
    // region (16.8M u16, dead until softmax).
    const size_t WS_NEED = (size_t)(2 * KEY_E + ATT_E + 2 * QW_E) * 2;

    if (ws_size >= WS_NEED && d_ws != nullptr) {
        u16* key_h  = (u16*)d_ws;
        u16* key_hT = key_h + KEY_E;
        u16* att_h  = key_hT + KEY_E;
        u16* qW_h   = att_h + ATT_E;
        // phase-1 scratch aliased into att_h (all dead by softmax time):
        u16* q_hi   = att_h;
        u16* q_lo   = q_hi + QW_E;
        u16* W_hiT  = q_lo + QW_E;
        u16* W_loT  = W_hiT + W_E;

        // 0a) key f32 -> key_h fp16 (pure grid-stride stream, ~5-6 TB/s)
        conv_f16<<<dim3(4096), 256, 0, stream>>>(key, key_h, KEY_E / 4);
        // 0b) key_h -> key_hT (tpos-swizzled transpose, conflict-free)
        transpose_u16<<<dim3(16, 32, 16), 256, 0, stream>>>(
            key_h, key_hT, 2048, 1024);
        // 0c) q -> fp16 hi+lo; W -> transposed fp16 hi+lo in ONE pass
        split_f16<<<dim3(512), 256, 0, stream>>>(query, q_hi, q_lo, QW_E / 4);
        splitT_f16<<<dim3(16, 16, 1), 256, 0, stream>>>(W, W_hiT, W_loT);

        // 1) qW = (query @ W) / 32  [512 x 1024], 3-term fp16 split, fp16 out
        gemm_qw<<<dim3(16, 8, 1), 256, 0, stream>>>(
            q_hi, q_lo, W_hiT, W_loT, qW_h);

        // 2) S[b] = qW @ key[b]^T   [512 x 2048], K=1024, 1-term fp16, BK=64
        gemm_f16<<<dim3(16, 4, 16), 256, 0, stream>>>(
            qW_h, key_h, att,
            1024, 1024, 1024, 2048,
            0L, (long)2048 * 1024, (long)512 * 2048, 1.f);

        // 3) masked softmax, dual-write f32 + fp16 (overwrites q/W scratch)
        softmax_rows<<<dim3(16 * 512), 256, 0, stream>>>(att, mask, att_h);

        // 4) out[b] = att[b] @ key[b]  [512 x 1024], K=2048, 1-term fp16, BK=64
        gemm_f16<<<dim3(8, 4, 16), 256, 0, stream>>>(
            att_h, key_hT, out,
            2048, 2048, 2048, 1024,
            (long)512 * 2048, (long)1024 * 2048, (long)512 * 1024, 1.f);
    } else {
        // -------- fallback: round-1 bf16 path, no workspace --------
        float* qW = out;    // f32 scratch in out region (dead before phase 4)
        gemm_f32conv<false, true><<<dim3(8, 4, 1), 256, 0, stream>>>(
            query, W, qW, 1024, 1024, 1024, 1024, 0L, 0L, 0L, 1.f / 32.f);
        gemm_f32conv<true, true><<<dim3(16, 4, 16), 256, 0, stream>>>(
            qW, key, att, 1024, 1024, 1024, 2048,
            0L, (long)2048 * 1024, (long)512 * 2048, 1.f);
        softmax_rows<<<dim3(16 * 512), 256, 0, stream>>>(att, mask, nullptr);
        gemm_f32conv<false, false><<<dim3(8, 4, 16), 256, 0, stream>>>(
            att, key, out, 2048, 2048, 1024, 1024,
            (long)512 * 2048, (long)2048 * 1024, (long)512 * 1024, 1.f);
    }
}

// Round 13
// 452.621 us; speedup vs baseline: 1.0440x; 1.0122x over previous
//
#include <hip/hip_runtime.h>

// SimpleConcatAttention on MI355X — round 13: double-buffered global_load_lds GEMM.
// Round-12 state: plateau ~455 µs; top-5 all harness fills (uncontrollable).
// gemm_f16 at MfmaUtil 17% with BOTH pipes ~7x under-saturated -> latency-bound
// serialization, not BW. Round-6's gload_lds failed because SINGLE-buffered
// (barrier->load->vmcnt(0)->compute = exposed latency). Correct form (catalog
// T3-minimum): DOUBLE buffer — issue next tile's gload_lds BEFORE this tile's
// compute; the end-of-iteration __syncthreads() (vmcnt drain + barrier) is the
// only sync. Load latency hides under 16 ds_read + 16 MFMA; 1 barrier/K-step;
// zero staging VGPRs. LDS: linear 16B chunks, bijection chunk(row,q) =
// row*4 + (q ^ ((row>>2)&3)) — per frag ds_read_b64 every bank gets exactly
// 4 dwords (the 512B/instr floor); staging inverse = 2 XORs.
// Only gemm_f16 changes; rest identical to round 12 (best-measured parts).

typedef float f32x4 __attribute__((ext_vector_type(4)));
typedef short s16x8 __attribute__((ext_vector_type(8)));
typedef short s16x4 __attribute__((ext_vector_type(4)));
typedef _Float16 f16x8 __attribute__((ext_vector_type(8)));
typedef unsigned short u16;
typedef unsigned short u16x8 __attribute__((ext_vector_type(8)));

// ---- conversions (compiler-visible; no inline asm per m240 lesson) ----
__device__ __forceinline__ u16 f2h(float f) {           // f32 -> fp16 RNE
    _Float16 h = (_Float16)f;
    return __builtin_bit_cast(u16, h);
}
__device__ __forceinline__ float h2f(u16 v) {           // exact expand
    return (float)__builtin_bit_cast(_Float16, v);
}
__device__ __forceinline__ u16 f2bf(float f) {          // bf16 RNE (fallback path)
    unsigned int u = __float_as_uint(f);
    return (u16)((u + 0x7fffu + ((u >> 16) & 1u)) >> 16);
}
__device__ __forceinline__ float bf2f(u16 h) {
    return __uint_as_float(((unsigned int)h) << 16);
}

// Load 8 u16 (two 8B halves) from LDS at two precomputed u16 offsets.
__device__ __forceinline__ s16x8 ld2(const u16* p, int off1, int off2) {
    s16x4 a = *(const s16x4*)(p + off1);
    s16x4 b = *(const s16x4*)(p + off2);
    s16x8 r = {a[0], a[1], a[2], a[3], b[0], b[1], b[2], b[3]};
    return r;
}
__device__ __forceinline__ f16x8 ld2h(const u16* p, int off1, int off2) {
    return __builtin_bit_cast(f16x8, ld2(p, off1, off2));
}

// Async 16B global -> LDS (direct DMA, no VGPR round-trip). HW writes at
// (wave-uniform lds base) + lane*16; the GLOBAL address is per-lane.
__device__ __forceinline__ void gload16(const u16* g, u16* l) {
    __builtin_amdgcn_global_load_lds(
        (const __attribute__((address_space(1))) unsigned int*)g,
        (__attribute__((address_space(3))) unsigned int*)l,
        16, 0, 0);
}

// GEMM tile LDS layout: [128 rows][32 k] fp16 as 512 16B-chunks.
// chunk(row, q) = row*4 + (q ^ ((row>>2)&3)), q = k>>3 (8 fp16 per chunk).
// u16 offset of element (row, k):
__device__ __forceinline__ int goff(int row, int k) {
    return (row * 4 + ((k >> 3) ^ ((row >> 2) & 3))) * 8 + (k & 7);
}

// Transpose-tile address (64x64 u16, col-major, stride 72): element (r, c)
// lives at col c, physical row-block (r>>3)^sigma(c), low bits r&7.
// sigma(c) = (c ^ (c>>3)) & 7 spreads scatter WRITES over all 32 banks;
// reads of 8 consecutive rows stay one aligned u16x8 (proven round 10:
// conflicts 7.6e6 -> 2.6e5).
__device__ __forceinline__ int tpos(int c, int rblk, int rlow) {
    const int s = (c ^ (c >> 3)) & 7;
    return c * 72 + 8 * ((rblk ^ s) & 7) + rlow;
}

// ===========================================================================
// Round-1 fused-conversion bf16 GEMM — fallback path only (ws too small).
// ===========================================================================
#define CSTR 36
typedef short bf16x8 __attribute__((ext_vector_type(8)));
__device__ __forceinline__ int swzc(int row, int k) {
    return row * CSTR + (k ^ (((row >> 2) & 7) << 2));
}
__device__ __forceinline__ bf16x8 ld_fragc(const u16* plane, int row, int kg) {
    s16x8 v = ld2(plane, swzc(row, kg), swzc(row, kg + 16));
    return __builtin_bit_cast(bf16x8, v);
}

template<bool BT, bool SPLIT>
__global__ __launch_bounds__(256, 2) void gemm_f32conv(
    const float* __restrict__ A, const float* __restrict__ B,
    float* __restrict__ C,
    int Kd, int lda, int ldb, int ldc,
    long sA, long sB, long sC, float scale)
{
    constexpr int PLANES = SPLIT ? 2 : 1;
    __shared__ u16 As[PLANES][128 * CSTR];
    __shared__ u16 Bs[PLANES][128 * CSTR];

    const int tid  = threadIdx.x;
    const int lane = tid & 63;
    const int wave = tid >> 6;
    const int wm = (wave >> 1) * 64, wn = (wave & 1) * 64;
    const int lr = lane & 15, kg = (lane >> 4) * 4;

    const int m0 = blockIdx.y * 128, n0 = blockIdx.x * 128;
    const float* Ag = A + (long)blockIdx.z * sA + (long)m0 * lda;
    const float* Bg = B + (long)blockIdx.z * sB + (BT ? (long)n0 * ldb : (long)n0);

    f32x4 acc[4][4] = {};

    for (int k0 = 0; k0 < Kd; k0 += 32) {
        __syncthreads();
#pragma unroll
        for (int it = 0; it < 4; it++) {
            const int idx = tid + it * 256;
            const int row = idx >> 3, kc = (idx & 7) * 4;
            f32x4 v = *(const f32x4*)(Ag + (long)row * lda + k0 + kc);
            ushort4 h;
            h.x = f2bf(v[0]); h.y = f2bf(v[1]); h.z = f2bf(v[2]); h.w = f2bf(v[3]);
            *(ushort4*)&As[0][swzc(row, kc)] = h;
            if constexpr (SPLIT) {
                ushort4 l;
                l.x = f2bf(v[0] - bf2f(h.x)); l.y = f2bf(v[1] - bf2f(h.y));
                l.z = f2bf(v[2] - bf2f(h.z)); l.w = f2bf(v[3] - bf2f(h.w));
                *(ushort4*)&As[1][swzc(row, kc)] = l;
            }
        }
        if constexpr (BT) {
#pragma unroll
            for (int it = 0; it < 4; it++) {
                const int idx = tid + it * 256;
                const int row = idx >> 3, kc = (idx & 7) * 4;
                f32x4 v = *(const f32x4*)(Bg + (long)row * ldb + k0 + kc);
                ushort4 h;
                h.x = f2bf(v[0]); h.y = f2bf(v[1]); h.z = f2bf(v[2]); h.w = f2bf(v[3]);
                *(ushort4*)&Bs[0][swzc(row, kc)] = h;
                if constexpr (SPLIT) {
                    ushort4 l;
                    l.x = f2bf(v[0] - bf2f(h.x)); l.y = f2bf(v[1] - bf2f(h.y));
                    l.z = f2bf(v[2] - bf2f(h.z)); l.w = f2bf(v[3] - bf2f(h.w));
                    *(ushort4*)&Bs[1][swzc(row, kc)] = l;
                }
            }
        } else {
#pragma unroll
            for (int it = 0; it < 2; it++) {
                const int idx = tid + it * 256;
                const int kk = (idx >> 5) * 2;
                const int nc = (idx & 31) * 4;
                f32x4 v0 = *(const f32x4*)(Bg + (long)(k0 + kk) * ldb + nc);
                f32x4 v1 = *(const f32x4*)(Bg + (long)(k0 + kk + 1) * ldb + nc);
#pragma unroll
                for (int e = 0; e < 4; e++) {
                    const u16 h0 = f2bf(v0[e]), h1 = f2bf(v1[e]);
                    *(unsigned*)&Bs[0][swzc(nc + e, kk)] =
                        (unsigned)h0 | ((unsigned)h1 << 16);
                    if constexpr (SPLIT) {
                        const u16 l0 = f2bf(v0[e] - bf2f(h0));
                        const u16 l1 = f2bf(v1[e] - bf2f(h1));
                        *(unsigned*)&Bs[1][swzc(nc + e, kk)] =
                            (unsigned)l0 | ((unsigned)l1 << 16);
                    }
                }
            }
        }
        __syncthreads();

        bf16x8 ah[4], bh[4], al[4], bl[4];
#pragma unroll
        for (int i = 0; i < 4; i++) {
            ah[i] = ld_fragc(&As[0][0], wm + i * 16 + lr, kg);
            if constexpr (SPLIT) al[i] = ld_fragc(&As[1][0], wm + i * 16 + lr, kg);
        }
#pragma unroll
        for (int j = 0; j < 4; j++) {
            bh[j] = ld_fragc(&Bs[0][0], wn + j * 16 + lr, kg);
            if constexpr (SPLIT) bl[j] = ld_fragc(&Bs[1][0], wn + j * 16 + lr, kg);
        }
#pragma unroll
        for (int i = 0; i < 4; i++)
#pragma unroll
            for (int j = 0; j < 4; j++) {
                acc[i][j] = __builtin_amdgcn_mfma_f32_16x16x32_bf16(
                    ah[i], bh[j], acc[i][j], 0, 0, 0);
                if constexpr (SPLIT) {
                    acc[i][j] = __builtin_amdgcn_mfma_f32_16x16x32_bf16(
                        ah[i], bl[j], acc[i][j], 0, 0, 0);
                    acc[i][j] = __builtin_amdgcn_mfma_f32_16x16x32_bf16(
                        al[i], bh[j], acc[i][j], 0, 0, 0);
                }
            }
    }

    float* Cg = C + (long)blockIdx.z * sC + (long)(m0 + wm) * ldc + n0 + wn;
    const int rbase = (lane >> 4) * 4;
#pragma unroll
    for (int i = 0; i < 4; i++)
#pragma unroll
        for (int r = 0; r < 4; r++) {
            float* cp = Cg + (long)(i * 16 + rbase + r) * ldc + lr;
#pragma unroll
            for (int j = 0; j < 4; j++)
                cp[j * 16] = acc[i][j][r] * scale;
        }
}

// ===========================================================================
// Streaming converters.
// ===========================================================================
__global__ __launch_bounds__(256) void conv_f16(
    const float* __restrict__ src, u16* __restrict__ dst, long n4)
{
    const long stride = (long)gridDim.x * 256;
    for (long i = (long)blockIdx.x * 256 + threadIdx.x; i < n4; i += stride) {
        f32x4 v = *(const f32x4*)(src + i * 4);
        ushort4 h;
        h.x = f2h(v[0]); h.y = f2h(v[1]); h.z = f2h(v[2]); h.w = f2h(v[3]);
        *(ushort4*)(dst + i * 4) = h;
    }
}

__global__ __launch_bounds__(256) void split_f16(
    const float* __restrict__ src, u16* __restrict__ hi, u16* __restrict__ lo,
    long n4)
{
    const long stride = (long)gridDim.x * 256;
    for (long i = (long)blockIdx.x * 256 + threadIdx.x; i < n4; i += stride) {
        f32x4 v = *(const f32x4*)(src + i * 4);
        ushort4 h, l;
        h.x = f2h(v[0]); h.y = f2h(v[1]); h.z = f2h(v[2]); h.w = f2h(v[3]);
        l.x = f2h(v[0] - h2f(h.x)); l.y = f2h(v[1] - h2f(h.y));
        l.z = f2h(v[2] - h2f(h.z)); l.w = f2h(v[3] - h2f(h.w));
        *(ushort4*)(hi + i * 4) = h;
        *(ushort4*)(lo + i * 4) = l;
    }
}

// ===========================================================================
// Batched u16 transpose: in [Z][R][C] -> out [Z][C][R]. R,C multiples of 64.
// tpos-swizzled 64x64 tile: conflict-free scatter writes, contiguous reads.
// ===========================================================================
__global__ __launch_bounds__(256) void transpose_u16(
    const u16* __restrict__ in, u16* __restrict__ out, int R, int C)
{
    __shared__ u16 T[64 * 72];
    const int tid = threadIdx.x;
    const int c0 = blockIdx.x * 64, r0 = blockIdx.y * 64;
    const long zo = (long)blockIdx.z * R * C;
    const u16* src = in + zo + (long)r0 * C + c0;
#pragma unroll
    for (int it = 0; it < 2; it++) {
        const int r = it * 32 + (tid >> 3), c = (tid & 7) * 8;
        u16x8 v = *(const u16x8*)(src + (long)r * C + c);
        const int rb = r >> 3, rl = r & 7;
#pragma unroll
        for (int j = 0; j < 8; j++) T[tpos(c + j, rb, rl)] = v[j];
    }
    __syncthreads();
    u16* dst = out + zo + (long)c0 * R + r0;
#pragma unroll
    for (int it = 0; it < 2; it++) {
        const int c = it * 32 + (tid >> 3);
        const int m = tid & 7;
        *(u16x8*)(dst + (long)c * R + m * 8) = *(const u16x8*)&T[tpos(c, m, 0)];
    }
}

// ===========================================================================
// Fused W split+transpose: f32 W [1024 k][1024 n] -> fp16 hiT/loT [n][k].
// ===========================================================================
__global__ __launch_bounds__(256) void splitT_f16(
    const float* __restrict__ src, u16* __restrict__ hiT, u16* __restrict__ loT)
{
    __shared__ u16 Th[64 * 72];
    __shared__ u16 Tl[64 * 72];
    const int tid = threadIdx.x;
    const int c0 = blockIdx.x * 64;             // n-cols
    const int r0 = blockIdx.y * 64;             // k-rows
    const float* s = src + (long)r0 * 1024 + c0;
#pragma unroll
    for (int it = 0; it < 2; it++) {
        const int r = it * 32 + (tid >> 3);     // k-row within tile
        const int c = (tid & 7) * 8;            // n-col within tile
        f32x4 v0 = *(const f32x4*)(s + (long)r * 1024 + c);
        f32x4 v1 = *(const f32x4*)(s + (long)r * 1024 + c + 4);
        const int rb = r >> 3, rl = r & 7;
#pragma unroll
        for (int j = 0; j < 8; j++) {
            const float f = (j < 4) ? v0[j] : v1[j - 4];
            const u16 h = f2h(f);
            Th[tpos(c + j, rb, rl)] = h;
            Tl[tpos(c + j, rb, rl)] = f2h(f - h2f(h));
        }
    }
    __syncthreads();
    u16* dh = hiT + (long)c0 * 1024 + r0;
    u16* dl = loT + (long)c0 * 1024 + r0;
#pragma unroll
    for (int it = 0; it < 2; it++) {
        const int c = it * 32 + (tid >> 3);     // n-col within tile
        const int m = tid & 7;                  // k row-block
        *(u16x8*)(dh + (long)c * 1024 + m * 8) = *(const u16x8*)&Th[tpos(c, m, 0)];
        *(u16x8*)(dl + (long)c * 1024 + m * 8) = *(const u16x8*)&Tl[tpos(c, m, 0)];
    }
}

// ===========================================================================
// fp16 MFMA GEMM, BK=32, DOUBLE-BUFFERED global_load_lds staging.
// Per K-step: issue next tile's 4 gload_lds (into buf^1), then ds_read+MFMA
// from buf, then ONE __syncthreads() (vmcnt+lgkm drain + barrier). Load
// latency hides under the compute phase. Zero staging VGPRs.
// LDS: per operand 2 x 512 16B-chunks; chunk(row,q) = row*4 + (q^((row>>2)&3)).
// Tile 128x128, 4 waves (64x64 each).
// ===========================================================================
__global__ __launch_bounds__(256, 4) void gemm_f16(
    const u16* __restrict__ A, const u16* __restrict__ B,
    float* __restrict__ C,
    int Kd, int lda, int ldb, int ldc,
    long sA, long sB, long sC, float scale)
{
    __shared__ u16 As[2 * 4096];
    __shared__ u16 Bs[2 * 4096];

    const int tid  = threadIdx.x;
    const int lane = tid & 63;
    const int wave = tid >> 6;
    const int wm = (wave >> 1) * 64, wn = (wave & 1) * 64;
    const int lr = lane & 15, kg = (lane >> 4) * 4;

    const int m0 = blockIdx.y * 128, n0 = blockIdx.x * 128;
    const u16* Ag = A + (long)blockIdx.z * sA + (long)m0 * lda;
    const u16* Bg = B + (long)blockIdx.z * sB + (long)n0 * ldb;

    // Staging geometry (loop-invariant): thread fills chunks p1=tid, p2=tid+256
    // per operand. Inverse bijection gives the global (row, k-col) per chunk.
    const int row1 = tid >> 2;
    const int kc1  = 8 * ((tid & 3) ^ ((row1 >> 2) & 3));
    const int row2 = row1 + 64;
    const int kc2  = 8 * ((tid & 3) ^ ((row2 >> 2) & 3));
    const int lb1  = (tid & ~63) * 8;         // wave-uniform u16 base, chunks w*64..
    const int lb2  = 2048 + lb1;              // +256 chunks

    f32x4 acc[4][4] = {};

    // ---- prologue: stage k=0 into buffer 0 ----
    gload16(Ag + (long)row1 * lda + kc1, &As[lb1]);
    gload16(Ag + (long)row2 * lda + kc2, &As[lb2]);
    gload16(Bg + (long)row1 * ldb + kc1, &Bs[lb1]);
    gload16(Bg + (long)row2 * ldb + kc2, &Bs[lb2]);
    __syncthreads();                          // vmcnt(0) drain + barrier

    int cur = 0;
    for (int k0 = 0; k0 < Kd; k0 += 32) {
        // ---- issue next tile's loads into the other buffer (no wait) ----
        if (k0 + 32 < Kd) {
            const int kn = k0 + 32;
            const int nb = (cur ^ 1) * 4096;
            gload16(Ag + (long)row1 * lda + kn + kc1, &As[nb + lb1]);
            gload16(Ag + (long)row2 * lda + kn + kc2, &As[nb + lb2]);
            gload16(Bg + (long)row1 * ldb + kn + kc1, &Bs[nb + lb1]);
            gload16(Bg + (long)row2 * ldb + kn + kc2, &Bs[nb + lb2]);
        }

        // ---- compute current buffer ----
        const u16* a = &As[cur * 4096];
        const u16* b = &Bs[cur * 4096];
        f16x8 af[4], bfr[4];
#pragma unroll
        for (int i = 0; i < 4; i++) {
            const int r = wm + i * 16 + lr;
            af[i] = ld2h(a, goff(r, kg), goff(r, kg + 16));
        }
#pragma unroll
        for (int j = 0; j < 4; j++) {
            const int r = wn + j * 16 + lr;
            bfr[j] = ld2h(b, goff(r, kg), goff(r, kg + 16));
        }
#pragma unroll
        for (int i = 0; i < 4; i++)
#pragma unroll
            for (int j = 0; j < 4; j++)
                acc[i][j] = __builtin_amdgcn_mfma_f32_16x16x32_f16(
                    af[i], bfr[j], acc[i][j], 0, 0, 0);

        __syncthreads();                      // drains vmcnt(0) (next-tile loads)
        cur ^= 1;                             // + barrier; buffer now safe to swap
    }

    // ---- epilogue: C/D layout col=lane&15, row=(lane>>4)*4+reg ----
    float* Cg = C + (long)blockIdx.z * sC + (long)(m0 + wm) * ldc + n0 + wn;
    const int rbase = (lane >> 4) * 4;
#pragma unroll
    for (int i = 0; i < 4; i++)
#pragma unroll
        for (int r = 0; r < 4; r++) {
            float* cp = Cg + (long)(i * 16 + rbase + r) * ldc + lr;
#pragma unroll
            for (int j = 0; j < 4; j++)
                cp[j * 16] = acc[i][j][r] * scale;
        }
}

// ===========================================================================
// Phase-1 kernel: qW = (query @ W)/32, 3-term fp16-split in, fp16 OUT.
// M=512, N=1024, K=1024, B = W^T planes [n][k]. Tile 64x64, 4 waves (32x32),
// 128 blocks; copy staging (pad-40), both operands k-contiguous.
// ===========================================================================
#define ASTR 40
__global__ __launch_bounds__(256, 2) void gemm_qw(
    const u16* __restrict__ qh, const u16* __restrict__ ql,
    const u16* __restrict__ WhT, const u16* __restrict__ WlT,
    u16* __restrict__ qWh)
{
    __shared__ u16 As[2][64 * ASTR];
    __shared__ u16 Bs[2][64 * ASTR];

    const int tid  = threadIdx.x;
    const int lane = tid & 63;
    const int wave = tid >> 6;
    const int wm = (wave >> 1) * 32, wn = (wave & 1) * 32;
    const int lr = lane & 15, kg = (lane >> 4) * 4;
    const int m0 = blockIdx.y * 64, n0 = blockIdx.x * 64;

    const u16* Ag[2] = { qh + (long)m0 * 1024, ql + (long)m0 * 1024 };
    const u16* Bg[2] = { WhT + (long)n0 * 1024, WlT + (long)n0 * 1024 };

    f32x4 acc[2][2] = {};

    for (int k0 = 0; k0 < 1024; k0 += 32) {
        __syncthreads();
        const int row = tid >> 2, kc = (tid & 3) * 8;   // 64 rows x 32 k per plane
#pragma unroll
        for (int p = 0; p < 2; p++) {
            *(u16x8*)&As[p][row * ASTR + kc] =
                *(const u16x8*)(Ag[p] + (long)row * 1024 + k0 + kc);
            *(u16x8*)&Bs[p][row * ASTR + kc] =
                *(const u16x8*)(Bg[p] + (long)row * 1024 + k0 + kc);
        }
        __syncthreads();

        f16x8 af[2][2], bfr[2][2];
#pragma unroll
        for (int i = 0; i < 2; i++) {
            const int r = wm + i * 16 + lr;
#pragma unroll
            for (int p = 0; p < 2; p++)
                af[p][i] = ld2h(&As[p][0], r * ASTR + kg, r * ASTR + kg + 16);
        }
#pragma unroll
        for (int j = 0; j < 2; j++) {
            const int r = wn + j * 16 + lr;
#pragma unroll
            for (int p = 0; p < 2; p++)
                bfr[p][j] = ld2h(&Bs[p][0], r * ASTR + kg, r * ASTR + kg + 16);
        }
#pragma unroll
        for (int i = 0; i < 2; i++)
#pragma unroll
            for (int j = 0; j < 2; j++) {
                acc[i][j] = __builtin_amdgcn_mfma_f32_16x16x32_f16(
                    af[0][i], bfr[0][j], acc[i][j], 0, 0, 0);
                acc[i][j] = __builtin_amdgcn_mfma_f32_16x16x32_f16(
                    af[0][i], bfr[1][j], acc[i][j], 0, 0, 0);
                acc[i][j] = __builtin_amdgcn_mfma_f32_16x16x32_f16(
                    af[1][i], bfr[0][j], acc[i][j], 0, 0, 0);
            }
    }

    // Epilogue: scale by 1/32, write fp16 qW.
    const int rbase = (lane >> 4) * 4;
#pragma unroll
    for (int i = 0; i < 2; i++)
#pragma unroll
        for (int r = 0; r < 4; r++) {
            const long ro = (long)(m0 + wm + i * 16 + rbase + r) * 1024 + n0 + wn + lr;
#pragma unroll
            for (int j = 0; j < 2; j++)
                qWh[ro + j * 16] = f2h(acc[i][j][r] * (1.f / 32.f));
        }
}

// ===========================================================================
// Masked softmax over rows of 2048, in place on f32 scores; optionally also
// writes an fp16 copy (phase-4 A operand). One block per row.
// ===========================================================================
__global__ __launch_bounds__(256) void softmax_rows(
    float* __restrict__ att, const int* __restrict__ mask, u16* __restrict__ ahf)
{
    const int  row  = blockIdx.x;                    // b*512 + k
    const int  tid  = threadIdx.x;
    const long base = (long)row * 2048 + tid * 8;

    f32x4 s0 = *(const f32x4*)(att + base);
    f32x4 s1 = *(const f32x4*)(att + base + 4);
    int4  mv0 = *(const int4*)(mask + base);
    int4  mv1 = *(const int4*)(mask + base + 4);
    const int mk[8] = {mv0.x, mv0.y, mv0.z, mv0.w, mv1.x, mv1.y, mv1.z, mv1.w};

    float x[8] = {s0[0], s0[1], s0[2], s0[3], s1[0], s1[1], s1[2], s1[3]};
#pragma unroll
    for (int j = 0; j < 8; j++) x[j] = mk[j] ? x[j] : -INFINITY;

    float mx = x[0];
#pragma unroll
    for (int j = 1; j < 8; j++) mx = fmaxf(mx, x[j]);
#pragma unroll
    for (int off = 32; off > 0; off >>= 1) mx = fmaxf(mx, __shfl_down(mx, off));

    __shared__ float red[8];
    const int wave = tid >> 6, lane = tid & 63;
    if (lane == 0) red[wave] = mx;
    __syncthreads();
    mx = fmaxf(fmaxf(red[0], red[1]), fmaxf(red[2], red[3]));

    if (mx == -INFINITY) {                           // all-masked row: zeros, not NaN
        f32x4 z = {0.f, 0.f, 0.f, 0.f};
        *(f32x4*)(att + base) = z;
        *(f32x4*)(att + base + 4) = z;
        if (ahf) {
            u16x8 zh = {0, 0, 0, 0, 0, 0, 0, 0};
            *(u16x8*)(ahf + base) = zh;
        }
        return;
    }

    float e[8], s = 0.f;
#pragma unroll
    for (int j = 0; j < 8; j++) { e[j] = __expf(x[j] - mx); s += e[j]; }
#pragma unroll
    for (int off = 32; off > 0; off >>= 1) s += __shfl_down(s, off);
    if (lane == 0) red[4 + wave] = s;
    __syncthreads();
    s = red[4] + red[5] + red[6] + red[7];

    const float inv = 1.f / s;
    float o[8];
#pragma unroll
    for (int j = 0; j < 8; j++) o[j] = e[j] * inv;
    f32x4 o0 = {o[0], o[1], o[2], o[3]}, o1 = {o[4], o[5], o[6], o[7]};
    *(f32x4*)(att + base) = o0;
    *(f32x4*)(att + base + 4) = o1;
    if (ahf) {
        u16x8 ph;
#pragma unroll
        for (int j = 0; j < 8; j++) ph[j] = f2h(o[j]);
        *(u16x8*)(ahf + base) = ph;
    }
}

// ===========================================================================
extern "C" void kernel_launch(void* const* d_in, const int* in_sizes, int n_in,
                              void* d_out, int out_size, void* d_ws, size_t ws_size,
                              hipStream_t stream)
{
    const float* query = nullptr;   // 512*1024      = 524288
    const float* key   = nullptr;   // 16*2048*1024  = 33554432
    const float* W     = nullptr;   // 1024*1024     = 1048576
    const int*   mask  = nullptr;   // 16*512*2048   = 16777216
    for (int i = 0; i < n_in; i++) {
        switch (in_sizes[i]) {
            case 524288:   query = (const float*)d_in[i]; break;
            case 33554432: key   = (const float*)d_in[i]; break;
            case 1048576:  W     = (const float*)d_in[i]; break;
            case 16777216: mask  = (const int*)d_in[i];   break;
        }
    }

    float* out = (float*)d_out;                     // [16,512,1024] f32
    float* att = out + (long)16 * 512 * 1024;       // [16,512,2048] f32

    const long KEY_E = 16L * 2048 * 1024;           // 33,554,432
    const long ATT_E = 16L * 512 * 2048;            // 16,777,216
    const long QW_E  = 512L * 1024;                 //    524,288
    const long W_E   = 1024L * 1024;                //  1,048,576
    // ws layout (same footprint/guard as rounds 4-12):
    //   key_h | key_hT | att_h | qW_h
    // Phase-1 scratch (q hi/lo, W^T hi/lo = 3.1M u16) aliases into the att_h
    // region (16.8M u16, dead until softmax).
    const size_t WS_NEED = (size_t)(2 * KEY_E + ATT_E + 2 * QW_E) * 2;

    if (ws_size >= WS_NEED && d_ws != nullptr) {
        u16* key_h  = (u16*)d_ws;
        u16* key_hT = key_h + KEY_E;
        u16* att_h  = key_hT + KEY_E;
        u16* qW_h   = att_h + ATT_E;
        // phase-1 scratch aliased into att_h (all dead by softmax time):
        u16* q_hi   = att_h;
        u16* q_lo   = q_hi + QW_E;
        u16* W_hiT  = q_lo + QW_E;
        u16* W_loT  = W_hiT + W_E;

        // 0a) key f32 -> key_h fp16 (pure grid-stride stream)
        conv_f16<<<dim3(4096), 256, 0, stream>>>(key, key_h, KEY_E / 4);
        // 0b) key_h -> key_hT (tpos-swizzled transpose, conflict-free)
        transpose_u16<<<dim3(16, 32, 16), 256, 0, stream>>>(
            key_h, key_hT, 2048, 1024);
        // 0c) q -> fp16 hi+lo; W -> transposed fp16 hi+lo in ONE pass
        split_f16<<<dim3(512), 256, 0, stream>>>(query, q_hi, q_lo, QW_E / 4);
        splitT_f16<<<dim3(16, 16, 1), 256, 0, stream>>>(W, W_hiT, W_loT);

        // 1) qW = (query @ W) / 32  [512 x 1024], 3-term fp16 split, fp16 out
        gemm_qw<<<dim3(16, 8, 1), 256, 0, stream>>>(
            q_hi, q_lo, W_hiT, W_loT, qW_h);

        // 2) S[b] = qW @ key[b]^T   [512 x 2048], K=1024, dbuf gload_lds GEMM
        gemm_f16<<<dim3(16, 4, 16), 256, 0, stream>>>(
            qW_h, key_h, att,
            1024, 1024, 1024, 2048,
            0L, (long)2048 * 1024, (long)512 * 2048, 1.f);

        // 3) masked softmax, dual-write f32 + fp16 (overwrites q/W scratch)
        softmax_rows<<<dim3(16 * 512), 256, 0, stream>>>(att, mask, att_h);

        // 4) out[b] = att[b] @ key[b]  [512 x 1024], K=2048, dbuf gload_lds GEMM
        gemm_f16<<<dim3(8, 4, 16), 256, 0, stream>>>(
            att_h, key_hT, out,
            2048, 2048, 2048, 1024,
            (long)512 * 2048, (long)1024 * 2048, (long)512 * 1024, 1.f);
    } else {
        // -------- fallback: round-1 bf16 path, no workspace --------
        float* qW = out;    // f32 scratch in out region (dead before phase 4)
        gemm_f32conv<false, true><<<dim3(8, 4, 1), 256, 0, stream>>>(
            query, W, qW, 1024, 1024, 1024, 1024, 0L, 0L, 0L, 1.f / 32.f);
        gemm_f32conv<true, true><<<dim3(16, 4, 16), 256, 0, stream>>>(
            qW, key, att, 1024, 1024, 1024, 2048,
            0L, (long)2048 * 1024, (long)512 * 2048, 1.f);
        softmax_rows<<<dim3(16 * 512), 256, 0, stream>>>(att, mask, nullptr);
        gemm_f32conv<false, false><<<dim3(8, 4, 16), 256, 0, stream>>>(
            att, key, out, 2048, 2048, 1024, 1024,
            (long)512 * 2048, (long)2048 * 1024, (long)512 * 1024, 1.f);
    }
}

// Round 14
// 446.955 us; speedup vs baseline: 1.0572x; 1.0127x over previous
//
#include <hip/hip_runtime.h>

// SimpleConcatAttention on MI355X — round 14: XCD-chunked block swizzle (T1).
// Round-13 post-mortem: dbuf gload_lds got conflicts to 0, ph2 < 77 µs, but
// ph4 = 81 µs with FETCH 185 MB vs ~100 ideal (1.85x over-fetch @ 2.7 TB/s):
// default dispatch round-robins consecutive blocks across 8 XCDs, so the
// 4.2 MB/batch key_hT panel thrashes every per-XCD L2. Fix: T1 chunked swizzle
// logical = (lin&7)*(nwg/8) + (lin>>3)  [bijective: nwg=1024/512, both %8==0]
// -> each XCD owns a contiguous run of tiles (~2 batches), L2 holds its own
// panels. Only gemm_f16 gains the remap; all else identical to round 13.

typedef float f32x4 __attribute__((ext_vector_type(4)));
typedef short s16x8 __attribute__((ext_vector_type(8)));
typedef short s16x4 __attribute__((ext_vector_type(4)));
typedef _Float16 f16x8 __attribute__((ext_vector_type(8)));
typedef unsigned short u16;
typedef unsigned short u16x8 __attribute__((ext_vector_type(8)));

// ---- conversions (compiler-visible; no inline asm per m240 lesson) ----
__device__ __forceinline__ u16 f2h(float f) {           // f32 -> fp16 RNE
    _Float16 h = (_Float16)f;
    return __builtin_bit_cast(u16, h);
}
__device__ __forceinline__ float h2f(u16 v) {           // exact expand
    return (float)__builtin_bit_cast(_Float16, v);
}
__device__ __forceinline__ u16 f2bf(float f) {          // bf16 RNE (fallback path)
    unsigned int u = __float_as_uint(f);
    return (u16)((u + 0x7fffu + ((u >> 16) & 1u)) >> 16);
}
__device__ __forceinline__ float bf2f(u16 h) {
    return __uint_as_float(((unsigned int)h) << 16);
}

// Load 8 u16 (two 8B halves) from LDS at two precomputed u16 offsets.
__device__ __forceinline__ s16x8 ld2(const u16* p, int off1, int off2) {
    s16x4 a = *(const s16x4*)(p + off1);
    s16x4 b = *(const s16x4*)(p + off2);
    s16x8 r = {a[0], a[1], a[2], a[3], b[0], b[1], b[2], b[3]};
    return r;
}
__device__ __forceinline__ f16x8 ld2h(const u16* p, int off1, int off2) {
    return __builtin_bit_cast(f16x8, ld2(p, off1, off2));
}

// Async 16B global -> LDS (direct DMA, no VGPR round-trip). HW writes at
// (wave-uniform lds base) + lane*16; the GLOBAL address is per-lane.
__device__ __forceinline__ void gload16(const u16* g, u16* l) {
    __builtin_amdgcn_global_load_lds(
        (const __attribute__((address_space(1))) unsigned int*)g,
        (__attribute__((address_space(3))) unsigned int*)l,
        16, 0, 0);
}

// GEMM tile LDS layout: [128 rows][32 k] fp16 as 512 16B-chunks.
// chunk(row, q) = row*4 + (q ^ ((row>>2)&3)), q = k>>3 (8 fp16 per chunk).
__device__ __forceinline__ int goff(int row, int k) {
    return (row * 4 + ((k >> 3) ^ ((row >> 2) & 3))) * 8 + (k & 7);
}

// Transpose-tile address (64x64 u16, col-major, stride 72): element (r, c)
// lives at col c, physical row-block (r>>3)^sigma(c), low bits r&7.
// sigma(c) = (c ^ (c>>3)) & 7 spreads scatter WRITES over all 32 banks;
// reads of 8 consecutive rows stay one aligned u16x8 (proven round 10:
// conflicts 7.6e6 -> 2.6e5).
__device__ __forceinline__ int tpos(int c, int rblk, int rlow) {
    const int s = (c ^ (c >> 3)) & 7;
    return c * 72 + 8 * ((rblk ^ s) & 7) + rlow;
}

// ===========================================================================
// Round-1 fused-conversion bf16 GEMM — fallback path only (ws too small).
// ===========================================================================
#define CSTR 36
typedef short bf16x8 __attribute__((ext_vector_type(8)));
__device__ __forceinline__ int swzc(int row, int k) {
    return row * CSTR + (k ^ (((row >> 2) & 7) << 2));
}
__device__ __forceinline__ bf16x8 ld_fragc(const u16* plane, int row, int kg) {
    s16x8 v = ld2(plane, swzc(row, kg), swzc(row, kg + 16));
    return __builtin_bit_cast(bf16x8, v);
}

template<bool BT, bool SPLIT>
__global__ __launch_bounds__(256, 2) void gemm_f32conv(
    const float* __restrict__ A, const float* __restrict__ B,
    float* __restrict__ C,
    int Kd, int lda, int ldb, int ldc,
    long sA, long sB, long sC, float scale)
{
    constexpr int PLANES = SPLIT ? 2 : 1;
    __shared__ u16 As[PLANES][128 * CSTR];
    __shared__ u16 Bs[PLANES][128 * CSTR];

    const int tid  = threadIdx.x;
    const int lane = tid & 63;
    const int wave = tid >> 6;
    const int wm = (wave >> 1) * 64, wn = (wave & 1) * 64;
    const int lr = lane & 15, kg = (lane >> 4) * 4;

    const int m0 = blockIdx.y * 128, n0 = blockIdx.x * 128;
    const float* Ag = A + (long)blockIdx.z * sA + (long)m0 * lda;
    const float* Bg = B + (long)blockIdx.z * sB + (BT ? (long)n0 * ldb : (long)n0);

    f32x4 acc[4][4] = {};

    for (int k0 = 0; k0 < Kd; k0 += 32) {
        __syncthreads();
#pragma unroll
        for (int it = 0; it < 4; it++) {
            const int idx = tid + it * 256;
            const int row = idx >> 3, kc = (idx & 7) * 4;
            f32x4 v = *(const f32x4*)(Ag + (long)row * lda + k0 + kc);
            ushort4 h;
            h.x = f2bf(v[0]); h.y = f2bf(v[1]); h.z = f2bf(v[2]); h.w = f2bf(v[3]);
            *(ushort4*)&As[0][swzc(row, kc)] = h;
            if constexpr (SPLIT) {
                ushort4 l;
                l.x = f2bf(v[0] - bf2f(h.x)); l.y = f2bf(v[1] - bf2f(h.y));
                l.z = f2bf(v[2] - bf2f(h.z)); l.w = f2bf(v[3] - bf2f(h.w));
                *(ushort4*)&As[1][swzc(row, kc)] = l;
            }
        }
        if constexpr (BT) {
#pragma unroll
            for (int it = 0; it < 4; it++) {
                const int idx = tid + it * 256;
                const int row = idx >> 3, kc = (idx & 7) * 4;
                f32x4 v = *(const f32x4*)(Bg + (long)row * ldb + k0 + kc);
                ushort4 h;
                h.x = f2bf(v[0]); h.y = f2bf(v[1]); h.z = f2bf(v[2]); h.w = f2bf(v[3]);
                *(ushort4*)&Bs[0][swzc(row, kc)] = h;
                if constexpr (SPLIT) {
                    ushort4 l;
                    l.x = f2bf(v[0] - bf2f(h.x)); l.y = f2bf(v[1] - bf2f(h.y));
                    l.z = f2bf(v[2] - bf2f(h.z)); l.w = f2bf(v[3] - bf2f(h.w));
                    *(ushort4*)&Bs[1][swzc(row, kc)] = l;
                }
            }
        } else {
#pragma unroll
            for (int it = 0; it < 2; it++) {
                const int idx = tid + it * 256;
                const int kk = (idx >> 5) * 2;
                const int nc = (idx & 31) * 4;
                f32x4 v0 = *(const f32x4*)(Bg + (long)(k0 + kk) * ldb + nc);
                f32x4 v1 = *(const f32x4*)(Bg + (long)(k0 + kk + 1) * ldb + nc);
#pragma unroll
                for (int e = 0; e < 4; e++) {
                    const u16 h0 = f2bf(v0[e]), h1 = f2bf(v1[e]);
                    *(unsigned*)&Bs[0][swzc(nc + e, kk)] =
                        (unsigned)h0 | ((unsigned)h1 << 16);
                    if constexpr (SPLIT) {
                        const u16 l0 = f2bf(v0[e] - bf2f(h0));
                        const u16 l1 = f2bf(v1[e] - bf2f(h1));
                        *(unsigned*)&Bs[1][swzc(nc + e, kk)] =
                            (unsigned)l0 | ((unsigned)l1 << 16);
                    }
                }
            }
        }
        __syncthreads();

        bf16x8 ah[4], bh[4], al[4], bl[4];
#pragma unroll
        for (int i = 0; i < 4; i++) {
            ah[i] = ld_fragc(&As[0][0], wm + i * 16 + lr, kg);
            if constexpr (SPLIT) al[i] = ld_fragc(&As[1][0], wm + i * 16 + lr, kg);
        }
#pragma unroll
        for (int j = 0; j < 4; j++) {
            bh[j] = ld_fragc(&Bs[0][0], wn + j * 16 + lr, kg);
            if constexpr (SPLIT) bl[j] = ld_fragc(&Bs[1][0], wn + j * 16 + lr, kg);
        }
#pragma unroll
        for (int i = 0; i < 4; i++)
#pragma unroll
            for (int j = 0; j < 4; j++) {
                acc[i][j] = __builtin_amdgcn_mfma_f32_16x16x32_bf16(
                    ah[i], bh[j], acc[i][j], 0, 0, 0);
                if constexpr (SPLIT) {
                    acc[i][j] = __builtin_amdgcn_mfma_f32_16x16x32_bf16(
                        ah[i], bl[j], acc[i][j], 0, 0, 0);
                    acc[i][j] = __builtin_amdgcn_mfma_f32_16x16x32_bf16(
                        al[i], bh[j], acc[i][j], 0, 0, 0);
                }
            }
    }

    float* Cg = C + (long)blockIdx.z * sC + (long)(m0 + wm) * ldc + n0 + wn;
    const int rbase = (lane >> 4) * 4;
#pragma unroll
    for (int i = 0; i < 4; i++)
#pragma unroll
        for (int r = 0; r < 4; r++) {
            float* cp = Cg + (long)(i * 16 + rbase + r) * ldc + lr;
#pragma unroll
            for (int j = 0; j < 4; j++)
                cp[j * 16] = acc[i][j][r] * scale;
        }
}

// ===========================================================================
// Streaming converters.
// ===========================================================================
__global__ __launch_bounds__(256) void conv_f16(
    const float* __restrict__ src, u16* __restrict__ dst, long n4)
{
    const long stride = (long)gridDim.x * 256;
    for (long i = (long)blockIdx.x * 256 + threadIdx.x; i < n4; i += stride) {
        f32x4 v = *(const f32x4*)(src + i * 4);
        ushort4 h;
        h.x = f2h(v[0]); h.y = f2h(v[1]); h.z = f2h(v[2]); h.w = f2h(v[3]);
        *(ushort4*)(dst + i * 4) = h;
    }
}

__global__ __launch_bounds__(256) void split_f16(
    const float* __restrict__ src, u16* __restrict__ hi, u16* __restrict__ lo,
    long n4)
{
    const long stride = (long)gridDim.x * 256;
    for (long i = (long)blockIdx.x * 256 + threadIdx.x; i < n4; i += stride) {
        f32x4 v = *(const f32x4*)(src + i * 4);
        ushort4 h, l;
        h.x = f2h(v[0]); h.y = f2h(v[1]); h.z = f2h(v[2]); h.w = f2h(v[3]);
        l.x = f2h(v[0] - h2f(h.x)); l.y = f2h(v[1] - h2f(h.y));
        l.z = f2h(v[2] - h2f(h.z)); l.w = f2h(v[3] - h2f(h.w));
        *(ushort4*)(hi + i * 4) = h;
        *(ushort4*)(lo + i * 4) = l;
    }
}

// ===========================================================================
// Batched u16 transpose: in [Z][R][C] -> out [Z][C][R]. R,C multiples of 64.
// tpos-swizzled 64x64 tile: conflict-free scatter writes, contiguous reads.
// ===========================================================================
__global__ __launch_bounds__(256) void transpose_u16(
    const u16* __restrict__ in, u16* __restrict__ out, int R, int C)
{
    __shared__ u16 T[64 * 72];
    const int tid = threadIdx.x;
    const int c0 = blockIdx.x * 64, r0 = blockIdx.y * 64;
    const long zo = (long)blockIdx.z * R * C;
    const u16* src = in + zo + (long)r0 * C + c0;
#pragma unroll
    for (int it = 0; it < 2; it++) {
        const int r = it * 32 + (tid >> 3), c = (tid & 7) * 8;
        u16x8 v = *(const u16x8*)(src + (long)r * C + c);
        const int rb = r >> 3, rl = r & 7;
#pragma unroll
        for (int j = 0; j < 8; j++) T[tpos(c + j, rb, rl)] = v[j];
    }
    __syncthreads();
    u16* dst = out + zo + (long)c0 * R + r0;
#pragma unroll
    for (int it = 0; it < 2; it++) {
        const int c = it * 32 + (tid >> 3);
        const int m = tid & 7;
        *(u16x8*)(dst + (long)c * R + m * 8) = *(const u16x8*)&T[tpos(c, m, 0)];
    }
}

// ===========================================================================
// Fused W split+transpose: f32 W [1024 k][1024 n] -> fp16 hiT/loT [n][k].
// ===========================================================================
__global__ __launch_bounds__(256) void splitT_f16(
    const float* __restrict__ src, u16* __restrict__ hiT, u16* __restrict__ loT)
{
    __shared__ u16 Th[64 * 72];
    __shared__ u16 Tl[64 * 72];
    const int tid = threadIdx.x;
    const int c0 = blockIdx.x * 64;             // n-cols
    const int r0 = blockIdx.y * 64;             // k-rows
    const float* s = src + (long)r0 * 1024 + c0;
#pragma unroll
    for (int it = 0; it < 2; it++) {
        const int r = it * 32 + (tid >> 3);     // k-row within tile
        const int c = (tid & 7) * 8;            // n-col within tile
        f32x4 v0 = *(const f32x4*)(s + (long)r * 1024 + c);
        f32x4 v1 = *(const f32x4*)(s + (long)r * 1024 + c + 4);
        const int rb = r >> 3, rl = r & 7;
#pragma unroll
        for (int j = 0; j < 8; j++) {
            const float f = (j < 4) ? v0[j] : v1[j - 4];
            const u16 h = f2h(f);
            Th[tpos(c + j, rb, rl)] = h;
            Tl[tpos(c + j, rb, rl)] = f2h(f - h2f(h));
        }
    }
    __syncthreads();
    u16* dh = hiT + (long)c0 * 1024 + r0;
    u16* dl = loT + (long)c0 * 1024 + r0;
#pragma unroll
    for (int it = 0; it < 2; it++) {
        const int c = it * 32 + (tid >> 3);     // n-col within tile
        const int m = tid & 7;                  // k row-block
        *(u16x8*)(dh + (long)c * 1024 + m * 8) = *(const u16x8*)&Th[tpos(c, m, 0)];
        *(u16x8*)(dl + (long)c * 1024 + m * 8) = *(const u16x8*)&Tl[tpos(c, m, 0)];
    }
}

// ===========================================================================
// fp16 MFMA GEMM, BK=32, double-buffered global_load_lds staging (round 13)
// + T1 XCD-chunked block swizzle: logical tile id = (lin&7)*(nwg/8)+(lin>>3)
// (bijective — both launches have nwg % 8 == 0). Each XCD gets a contiguous
// run of tiles, so its private L2 keeps the shared key/att panels resident.
// Tile 128x128, 4 waves (64x64 each); conflict-free chunked LDS (goff).
// ===========================================================================
__global__ __launch_bounds__(256, 4) void gemm_f16(
    const u16* __restrict__ A, const u16* __restrict__ B,
    float* __restrict__ C,
    int Kd, int lda, int ldb, int ldc,
    long sA, long sB, long sC, float scale)
{
    __shared__ u16 As[2 * 4096];
    __shared__ u16 Bs[2 * 4096];

    const int tid  = threadIdx.x;
    const int lane = tid & 63;
    const int wave = tid >> 6;
    const int wm = (wave >> 1) * 64, wn = (wave & 1) * 64;
    const int lr = lane & 15, kg = (lane >> 4) * 4;

    // ---- T1 XCD-chunked swizzle (hw linear id -> logical tile id) ----
    const int gx = gridDim.x, gy = gridDim.y;
    const int nwg = gx * gy * gridDim.z;
    const int lin = blockIdx.x + gx * (blockIdx.y + gy * blockIdx.z);
    const int swz = (lin & 7) * (nwg >> 3) + (lin >> 3);
    const int bx  = swz % gx;
    const int rem = swz / gx;
    const int by  = rem % gy;
    const int bz  = rem / gy;

    const int m0 = by * 128, n0 = bx * 128;
    const u16* Ag = A + (long)bz * sA + (long)m0 * lda;
    const u16* Bg = B + (long)bz * sB + (long)n0 * ldb;

    // Staging geometry (loop-invariant): thread fills chunks p1=tid, p2=tid+256
    // per operand. Inverse bijection gives the global (row, k-col) per chunk.
    const int row1 = tid >> 2;
    const int kc1  = 8 * ((tid & 3) ^ ((row1 >> 2) & 3));
    const int row2 = row1 + 64;
    const int kc2  = 8 * ((tid & 3) ^ ((row2 >> 2) & 3));
    const int lb1  = (tid & ~63) * 8;         // wave-uniform u16 base
    const int lb2  = 2048 + lb1;              // +256 chunks

    f32x4 acc[4][4] = {};

    // ---- prologue: stage k=0 into buffer 0 ----
    gload16(Ag + (long)row1 * lda + kc1, &As[lb1]);
    gload16(Ag + (long)row2 * lda + kc2, &As[lb2]);
    gload16(Bg + (long)row1 * ldb + kc1, &Bs[lb1]);
    gload16(Bg + (long)row2 * ldb + kc2, &Bs[lb2]);
    __syncthreads();                          // vmcnt(0) drain + barrier

    int cur = 0;
    for (int k0 = 0; k0 < Kd; k0 += 32) {
        // ---- issue next tile's loads into the other buffer (no wait) ----
        if (k0 + 32 < Kd) {
            const int kn = k0 + 32;
            const int nb = (cur ^ 1) * 4096;
            gload16(Ag + (long)row1 * lda + kn + kc1, &As[nb + lb1]);
            gload16(Ag + (long)row2 * lda + kn + kc2, &As[nb + lb2]);
            gload16(Bg + (long)row1 * ldb + kn + kc1, &Bs[nb + lb1]);
            gload16(Bg + (long)row2 * ldb + kn + kc2, &Bs[nb + lb2]);
        }

        // ---- compute current buffer ----
        const u16* a = &As[cur * 4096];
        const u16* b = &Bs[cur * 4096];
        f16x8 af[4], bfr[4];
#pragma unroll
        for (int i = 0; i < 4; i++) {
            const int r = wm + i * 16 + lr;
            af[i] = ld2h(a, goff(r, kg), goff(r, kg + 16));
        }
#pragma unroll
        for (int j = 0; j < 4; j++) {
            const int r = wn + j * 16 + lr;
            bfr[j] = ld2h(b, goff(r, kg), goff(r, kg + 16));
        }
#pragma unroll
        for (int i = 0; i < 4; i++)
#pragma unroll
            for (int j = 0; j < 4; j++)
                acc[i][j] = __builtin_amdgcn_mfma_f32_16x16x32_f16(
                    af[i], bfr[j], acc[i][j], 0, 0, 0);

        __syncthreads();                      // drains vmcnt(0) (next-tile loads)
        cur ^= 1;                             // + barrier; buffer safe to swap
    }

    // ---- epilogue: C/D layout col=lane&15, row=(lane>>4)*4+reg ----
    float* Cg = C + (long)bz * sC + (long)(m0 + wm) * ldc + n0 + wn;
    const int rbase = (lane >> 4) * 4;
#pragma unroll
    for (int i = 0; i < 4; i++)
#pragma unroll
        for (int r = 0; r < 4; r++) {
            float* cp = Cg + (long)(i * 16 + rbase + r) * ldc + lr;
#pragma unroll
            for (int j = 0; j < 4; j++)
                cp[j * 16] = acc[i][j][r] * scale;
        }
}

// ===========================================================================
// Phase-1 kernel: qW = (query @ W)/32, 3-term fp16-split in, fp16 OUT.
// M=512, N=1024, K=1024, B = W^T planes [n][k]. Tile 64x64, 4 waves (32x32),
// 128 blocks; copy staging (pad-40), both operands k-contiguous.
// ===========================================================================
#define ASTR 40
__global__ __launch_bounds__(256, 2) void gemm_qw(
    const u16* __restrict__ qh, const u16* __restrict__ ql,
    const u16* __restrict__ WhT, const u16* __restrict__ WlT,
    u16* __restrict__ qWh)
{
    __shared__ u16 As[2][64 * ASTR];
    __shared__ u16 Bs[2][64 * ASTR];

    const int tid  = threadIdx.x;
    const int lane = tid & 63;
    const int wave = tid >> 6;
    const int wm = (wave >> 1) * 32, wn = (wave & 1) * 32;
    const int lr = lane & 15, kg = (lane >> 4) * 4;
    const int m0 = blockIdx.y * 64, n0 = blockIdx.x * 64;

    const u16* Ag[2] = { qh + (long)m0 * 1024, ql + (long)m0 * 1024 };
    const u16* Bg[2] = { WhT + (long)n0 * 1024, WlT + (long)n0 * 1024 };

    f32x4 acc[2][2] = {};

    for (int k0 = 0; k0 < 1024; k0 += 32) {
        __syncthreads();
        const int row = tid >> 2, kc = (tid & 3) * 8;   // 64 rows x 32 k per plane
#pragma unroll
        for (int p = 0; p < 2; p++) {
            *(u16x8*)&As[p][row * ASTR + kc] =
                *(const u16x8*)(Ag[p] + (long)row * 1024 + k0 + kc);
            *(u16x8*)&Bs[p][row * ASTR + kc] =
                *(const u16x8*)(Bg[p] + (long)row * 1024 + k0 + kc);
        }
        __syncthreads();

        f16x8 af[2][2], bfr[2][2];
#pragma unroll
        for (int i = 0; i < 2; i++) {
            const int r = wm + i * 16 + lr;
#pragma unroll
            for (int p = 0; p < 2; p++)
                af[p][i] = ld2h(&As[p][0], r * ASTR + kg, r * ASTR + kg + 16);
        }
#pragma unroll
        for (int j = 0; j < 2; j++) {
            const int r = wn + j * 16 + lr;
#pragma unroll
            for (int p = 0; p < 2; p++)
                bfr[p][j] = ld2h(&Bs[p][0], r * ASTR + kg, r * ASTR + kg + 16);
        }
#pragma unroll
        for (int i = 0; i < 2; i++)
#pragma unroll
            for (int j = 0; j < 2; j++) {
                acc[i][j] = __builtin_amdgcn_mfma_f32_16x16x32_f16(
                    af[0][i], bfr[0][j], acc[i][j], 0, 0, 0);
                acc[i][j] = __builtin_amdgcn_mfma_f32_16x16x32_f16(
                    af[0][i], bfr[1][j], acc[i][j], 0, 0, 0);
                acc[i][j] = __builtin_amdgcn_mfma_f32_16x16x32_f16(
                    af[1][i], bfr[0][j], acc[i][j], 0, 0, 0);
            }
    }

    // Epilogue: scale by 1/32, write fp16 qW.
    const int rbase = (lane >> 4) * 4;
#pragma unroll
    for (int i = 0; i < 2; i++)
#pragma unroll
        for (int r = 0; r < 4; r++) {
            const long ro = (long)(m0 + wm + i * 16 + rbase + r) * 1024 + n0 + wn + lr;
#pragma unroll
            for (int j = 0; j < 2; j++)
                qWh[ro + j * 16] = f2h(acc[i][j][r] * (1.f / 32.f));
        }
}

// ===========================================================================
// Masked softmax over rows of 2048, in place on f32 scores; optionally also
// writes an fp16 copy (phase-4 A operand). One block per row.
// ===========================================================================
__global__ __launch_bounds__(256) void softmax_rows(
    float* __restrict__ att, const int* __restrict__ mask, u16* __restrict__ ahf)
{
    const int  row  = blockIdx.x;                    // b*512 + k
    const int  tid  = threadIdx.x;
    const long base = (long)row * 2048 + tid * 8;

    f32x4 s0 = *(const f32x4*)(att + base);
    f32x4 s1 = *(const f32x4*)(att + base + 4);
    int4  mv0 = *(const int4*)(mask + base);
    int4  mv1 = *(const int4*)(mask + base + 4);
    const int mk[8] = {mv0.x, mv0.y, mv0.z, mv0.w, mv1.x, mv1.y, mv1.z, mv1.w};

    float x[8] = {s0[0], s0[1], s0[2], s0[3], s1[0], s1[1], s1[2], s1[3]};
#pragma unroll
    for (int j = 0; j < 8; j++) x[j] = mk[j] ? x[j] : -INFINITY;

    float mx = x[0];
#pragma unroll
    for (int j = 1; j < 8; j++) mx = fmaxf(mx, x[j]);
#pragma unroll
    for (int off = 32; off > 0; off >>= 1) mx = fmaxf(mx, __shfl_down(mx, off));

    __shared__ float red[8];
    const int wave = tid >> 6, lane = tid & 63;
    if (lane == 0) red[wave] = mx;
    __syncthreads();
    mx = fmaxf(fmaxf(red[0], red[1]), fmaxf(red[2], red[3]));

    if (mx == -INFINITY) {                           // all-masked row: zeros, not NaN
        f32x4 z = {0.f, 0.f, 0.f, 0.f};
        *(f32x4*)(att + base) = z;
        *(f32x4*)(att + base + 4) = z;
        if (ahf) {
            u16x8 zh = {0, 0, 0, 0, 0, 0, 0, 0};
            *(u16x8*)(ahf + base) = zh;
        }
        return;
    }

    float e[8], s = 0.f;
#pragma unroll
    for (int j = 0; j < 8; j++) { e[j] = __expf(x[j] - mx); s += e[j]; }
#pragma unroll
    for (int off = 32; off > 0; off >>= 1) s += __shfl_down(s, off);
    if (lane == 0) red[4 + wave] = s;
    __syncthreads();
    s = red[4] + red[5] + red[6] + red[7];

    const float inv = 1.f / s;
    float o[8];
#pragma unroll
    for (int j = 0; j < 8; j++) o[j] = e[j] * inv;
    f32x4 o0 = {o[0], o[1], o[2], o[3]}, o1 = {o[4], o[5], o[6], o[7]};
    *(f32x4*)(att + base) = o0;
    *(f32x4*)(att + base + 4) = o1;
    if (ahf) {
        u16x8 ph;
#pragma unroll
        for (int j = 0; j < 8; j++) ph[j] = f2h(o[j]);
        *(u16x8*)(ahf + base) = ph;
    }
}

// ===========================================================================
extern "C" void kernel_launch(void* const* d_in, const int* in_sizes, int n_in,
                              void* d_out, int out_size, void* d_ws, size_t ws_size,
                              hipStream_t stream)
{
    const float* query = nullptr;   // 512*1024      = 524288
    const float* key   = nullptr;   // 16*2048*1024  = 33554432
    const float* W     = nullptr;   // 1024*1024     = 1048576
    const int*   mask  = nullptr;   // 16*512*2048   = 16777216
    for (int i = 0; i < n_in; i++) {
        switch (in_sizes[i]) {
            case 524288:   query = (const float*)d_in[i]; break;
            case 33554432: key   = (const float*)d_in[i]; break;
            case 1048576:  W     = (const float*)d_in[i]; break;
            case 16777216: mask  = (const int*)d_in[i];   break;
        }
    }

    float* out = (float*)d_out;                     // [16,512,1024] f32
    float* att = out + (long)16 * 512 * 1024;       // [16,512,2048] f32

    const long KEY_E = 16L * 2048 * 1024;           // 33,554,432
    const long ATT_E = 16L * 512 * 2048;            // 16,777,216
    const long QW_E  = 512L * 1024;                 //    524,288
    const long W_E   = 1024L * 1024;                //  1,048,576
    // ws layout (same footprint/guard as rounds 4-13):
    //   key_h | key_hT | att_h | qW_h
    // Phase-1 scratch (q hi/lo, W^T hi/lo = 3.1M u16) aliases into the att_h
    // region (16.8M u16, dead until softmax).
    const size_t WS_NEED = (size_t)(2 * KEY_E + ATT_E + 2 * QW_E) * 2;

    if (ws_size >= WS_NEED && d_ws != nullptr) {
        u16* key_h  = (u16*)d_ws;
        u16* key_hT = key_h + KEY_E;
        u16* att_h  = key_hT + KEY_E;
        u16* qW_h   = att_h + ATT_E;
        // phase-1 scratch aliased into att_h (all dead by softmax time):
        u16* q_hi   = att_h;
        u16* q_lo   = q_hi + QW_E;
        u16* W_hiT  = q_lo + QW_E;
        u16* W_loT  = W_hiT + W_E;

        // 0a) key f32 -> key_h fp16 (pure grid-stride stream)
        conv_f16<<<dim3(4096), 256, 0, stream>>>(key, key_h, KEY_E / 4);
        // 0b) key_h -> key_hT (tpos-swizzled transpose, conflict-free)
        transpose_u16<<<dim3(16, 32, 16), 256, 0, stream>>>(
            key_h, key_hT, 2048, 1024);
        // 0c) q -> fp16 hi+lo; W -> transposed fp16 hi+lo in ONE pass
        split_f16<<<dim3(512), 256, 0, stream>>>(query, q_hi, q_lo, QW_E / 4);
        splitT_f16<<<dim3(16, 16, 1), 256, 0, stream>>>(W, W_hiT, W_loT);

        // 1) qW = (query @ W) / 32  [512 x 1024], 3-term fp16 split, fp16 out
        gemm_qw<<<dim3(16, 8, 1), 256, 0, stream>>>(
            q_hi, q_lo, W_hiT, W_loT, qW_h);

        // 2) S[b] = qW @ key[b]^T   [512 x 2048], K=1024, dbuf + XCD swizzle
        //    nwg = 16*4*16 = 1024 (% 8 == 0 -> bijective swizzle)
        gemm_f16<<<dim3(16, 4, 16), 256, 0, stream>>>(
            qW_h, key_h, att,
            1024, 1024, 1024, 2048,
            0L, (long)2048 * 1024, (long)512 * 2048, 1.f);

        // 3) masked softmax, dual-write f32 + fp16 (overwrites q/W scratch)
        softmax_rows<<<dim3(16 * 512), 256, 0, stream>>>(att, mask, att_h);

        // 4) out[b] = att[b] @ key[b]  [512 x 1024], K=2048, dbuf + XCD swizzle
        //    nwg = 8*4*16 = 512 (% 8 == 0 -> bijective swizzle)
        gemm_f16<<<dim3(8, 4, 16), 256, 0, stream>>>(
            att_h, key_hT, out,
            2048, 2048, 2048, 1024,
            (long)512 * 2048, (long)1024 * 2048, (long)512 * 1024, 1.f);
    } else {
        // -------- fallback: round-1 bf16 path, no workspace --------
        float* qW = out;    // f32 scratch in out region (dead before phase 4)
        gemm_f32conv<false, true><<<dim3(8, 4, 1), 256, 0, stream>>>(
            query, W, qW, 1024, 1024, 1024, 1024, 0L, 0L, 0L, 1.f / 32.f);
        gemm_f32conv<true, true><<<dim3(16, 4, 16), 256, 0, stream>>>(
            qW, key, att, 1024, 1024, 1024, 2048,
            0L, (long)2048 * 1024, (long)512 * 2048, 1.f);
        softmax_rows<<<dim3(16 * 512), 256, 0, stream>>>(att, mask, nullptr);
        gemm_f32conv<false, false><<<dim3(8, 4, 16), 256, 0, stream>>>(
            att, key, out, 2048, 2048, 1024, 1024,
            (long)512 * 2048, (long)2048 * 1024, (long)512 * 1024, 1.f);
    }
}